// Round 1
// baseline (617.578 us; speedup 1.0000x reference)
//
#include <hip/hip_runtime.h>

typedef float fx4 __attribute__((ext_vector_type(4)));
typedef short s8 __attribute__((ext_vector_type(8)));
typedef short s4 __attribute__((ext_vector_type(4)));

#define MTOT 16384
#define NPTS 4096

__device__ __forceinline__ float b2f(short s) {
    return __uint_as_float(((unsigned)(unsigned short)s) << 16);
}
__device__ __forceinline__ short f2b(float f) {
    unsigned u = __float_as_uint(f);
    u += 0x7fffu + ((u >> 16) & 1u);
    return (short)(u >> 16);
}

// ---------------------------------------------------------------------------
// Weight transpose + bf16 convert: W[K][N] f32 -> Bt[N][Kp] bf16 (zero pad K..Kp)
// ---------------------------------------------------------------------------
__global__ void wtrans_kernel(const float* __restrict__ W, short* __restrict__ Bt,
                              int K, int N, int Kp)
{
    int idx = blockIdx.x * 256 + threadIdx.x;
    if (idx >= N * Kp) return;
    int n = idx / Kp, k = idx - n * Kp;
    Bt[idx] = (k < K) ? f2b(W[(size_t)k * N + n]) : (short)0;
}

// ---------------------------------------------------------------------------
// kNN + boundary info. grid = 256 blocks (4 batches x 64 chunks of 64 points).
// 4 threads per point, each scans a 1024-point quarter keeping sorted top-12.
// ---------------------------------------------------------------------------
#define XSP 1032  // 1024 + 8 stagger so the 4 quarters land in different banks

__global__ __launch_bounds__(256) void knn_kernel(
    const float* __restrict__ pos, const int* __restrict__ labels,
    const float* __restrict__ logits, float* __restrict__ info32)
{
    __shared__ float xs[4 * XSP], ys[4 * XSP], zs[4 * XSP];  // 49,536 B
    __shared__ unsigned short labs[NPTS];                     //  8,192 B

    int b = blockIdx.x >> 6;
    int pc = blockIdx.x & 63;
    int tid = threadIdx.x;

    for (int idx = tid; idx < NPTS; idx += 256) {
        int st = (idx >> 10) * XSP + (idx & 1023);
        const float* pp = pos + (size_t)(b * NPTS + idx) * 3;
        xs[st] = pp[0]; ys[st] = pp[1]; zs[st] = pp[2];
        labs[idx] = (unsigned short)labels[b * NPTS + idx];
    }
    __syncthreads();

    int i_loc = tid >> 2, q = tid & 3;
    int i = pc * 64 + i_loc;
    int ist = (i >> 10) * XSP + (i & 1023);
    float mx = xs[ist], my = ys[ist], mz = zs[ist];
    int mylab = (int)labs[i];

    float hd[12]; int hl[12];
#pragma unroll
    for (int k = 0; k < 12; ++k) { hd[k] = 3.0e38f; hl[k] = 0; }

    int jq0 = q * 1024;
    int qb = q * XSP;
    for (int jj = 0; jj < 1024; jj += 4) {
        fx4 xv = *reinterpret_cast<fx4*>(&xs[qb + jj]);
        fx4 yv = *reinterpret_cast<fx4*>(&ys[qb + jj]);
        fx4 zv = *reinterpret_cast<fx4*>(&zs[qb + jj]);
#pragma unroll
        for (int u = 0; u < 4; ++u) {
            float dx = xv[u] - mx, dy = yv[u] - my, dz = zv[u] - mz;
            float d2 = fmaf(dx, dx, fmaf(dy, dy, dz * dz));
            int j = jq0 + jj + u;
            if (j == i) d2 = 3.0e38f;
            if (d2 < hd[11]) {
                hd[11] = d2; hl[11] = (int)labs[j];
#pragma unroll
                for (int k = 11; k >= 1; --k) {
                    if (hd[k] < hd[k - 1]) {
                        float td = hd[k]; hd[k] = hd[k - 1]; hd[k - 1] = td;
                        int tl = hl[k]; hl[k] = hl[k - 1]; hl[k - 1] = tl;
                    }
                }
            }
        }
    }

    // reuse xs/ys as candidate buffers (all scans done after this barrier)
    __syncthreads();
    float* cd = xs;               // 64*48 floats = 12,288 B <= 16,512 B
    int*   cl = (int*)ys;
    int cbase = (i_loc * 4 + q) * 12;
#pragma unroll
    for (int k = 0; k < 12; ++k) { cd[cbase + k] = hd[k]; cl[cbase + k] = hl[k]; }
    __syncthreads();

    if (q != 0) return;

    // merge 4 sorted 12-lists -> top 12
    int base = i_loc * 48;
    int p0 = 0, p1 = 0, p2 = 0, p3 = 0;
    float dist[12];
    float sum_d = 0.f, sum_diff = 0.f, sum_same_d = 0.f, nsame = 0.f, bmin = 3.0e38f;
#pragma unroll
    for (int r = 0; r < 12; ++r) {
        float d0 = (p0 < 12) ? cd[base + p0]      : 3.0e38f;
        float d1 = (p1 < 12) ? cd[base + 12 + p1] : 3.0e38f;
        float d2 = (p2 < 12) ? cd[base + 24 + p2] : 3.0e38f;
        float d3 = (p3 < 12) ? cd[base + 36 + p3] : 3.0e38f;
        float mm = fminf(fminf(d0, d1), fminf(d2, d3));
        int c, off;
        if (mm == d0)      { c = 0; off = p0; ++p0; }
        else if (mm == d1) { c = 1; off = p1; ++p1; }
        else if (mm == d2) { c = 2; off = p2; ++p2; }
        else               { c = 3; off = p3; ++p3; }
        float dr = sqrtf(mm);
        int lb = cl[base + c * 12 + off];
        dist[r] = dr;
        sum_d += dr;
        if (lb != mylab) { sum_diff += 1.f; bmin = fminf(bmin, dr); }
        else             { sum_same_d += dr; nsame += 1.f; }
    }
    float mean_d = sum_d * (1.0f / 12.0f);
    float var = 0.f;
#pragma unroll
    for (int r = 0; r < 12; ++r) { float t = dist[r] - mean_d; var = fmaf(t, t, var); }
    var *= (1.0f / 11.0f);
    float md_eps = mean_d + 1e-6f;
    float curvature = sqrtf(var) / md_eps;
    float density = 1.0f / md_eps;
    float same_dist = sum_same_d / (nsame + 1e-6f);
    float bdist = (bmin < 2.9e38f) ? bmin : same_dist;
    float bscore = sum_diff * (1.0f / 12.0f);

    // softmax(logits / 0.75) -> confidence, entropy
    const float* lg = logits + (size_t)(b * NPTS + i) * 17;
    float v[17];
    float vmax = -3.0e38f;
#pragma unroll
    for (int c2 = 0; c2 < 17; ++c2) { v[c2] = lg[c2] * (1.0f / 0.75f); vmax = fmaxf(vmax, v[c2]); }
    float ssum = 0.f;
#pragma unroll
    for (int c2 = 0; c2 < 17; ++c2) { v[c2] = expf(v[c2] - vmax); ssum += v[c2]; }
    float inv = 1.0f / ssum;
    float conf = 0.f, ent = 0.f;
#pragma unroll
    for (int c2 = 0; c2 < 17; ++c2) {
        float pprob = v[c2] * inv;
        conf = fmaxf(conf, pprob);
        ent += pprob * logf(pprob + 1e-8f);
    }
    ent = -ent * (1.0f / 2.8332133f);  // / ln(17)

    float* op = info32 + (size_t)(b * NPTS + i) * 32;
    fx4 o0 = {bscore, conf, ent, density};
    fx4 o1 = {curvature, bdist, 0.f, 0.f};
    fx4 zz = {0.f, 0.f, 0.f, 0.f};
    *reinterpret_cast<fx4*>(op + 0)  = o0;
    *reinterpret_cast<fx4*>(op + 4)  = o1;
    *reinterpret_cast<fx4*>(op + 8)  = zz;
    *reinterpret_cast<fx4*>(op + 12) = zz;
    *reinterpret_cast<fx4*>(op + 16) = zz;
    *reinterpret_cast<fx4*>(op + 20) = zz;
    *reinterpret_cast<fx4*>(op + 24) = zz;
    *reinterpret_cast<fx4*>(op + 28) = zz;
}

// ---------------------------------------------------------------------------
// Fused 3-scale projection: fp_s = feat_s @ Wp_s + bp_s (bf16 out),
// global = mean_s fp_s (bf16 into attn_in cols 0..319, f32 into gf32).
// BM=128, BN=64, BK=32, 4 waves (2x2), grid = 128*5.
// ---------------------------------------------------------------------------
__global__ __launch_bounds__(256) void proj_kernel(
    const float* __restrict__ f0, const float* __restrict__ f1, const float* __restrict__ f2,
    const short* __restrict__ bt0, const short* __restrict__ bt1, const short* __restrict__ bt2,
    const float* __restrict__ bp0, const float* __restrict__ bp1, const float* __restrict__ bp2,
    short* __restrict__ fpout, short* __restrict__ attn_in, float* __restrict__ gf32)
{
    __shared__ short As[128 * 40];
    __shared__ short Bs[64 * 40];
    int bid = blockIdx.x;
    int mt = bid / 5, nt = bid % 5;
    int m0 = mt * 128, n0 = nt * 64;
    int tid = threadIdx.x, l = tid & 63, wid = tid >> 6;
    int wm = wid & 1, wn = wid >> 1, lr = l & 15, lh = l >> 4;
    fx4 gacc[4][2] = {};

    for (int s = 0; s < 3; ++s) {
        const float* A = (s == 0) ? f0 : (s == 1 ? f1 : f2);
        const short* Bt = (s == 0) ? bt0 : (s == 1 ? bt1 : bt2);
        const float* bias = (s == 0) ? bp0 : (s == 1 ? bp1 : bp2);
        int K = (s == 0) ? 256 : (s == 1 ? 512 : 768);
        fx4 acc[4][2] = {};
        int nsteps = K >> 5;
        for (int kt = 0; kt < nsteps; ++kt) {
            int k0 = kt << 5;
#pragma unroll
            for (int it = 0; it < 4; ++it) {
                int tt = tid + it * 256;
                int row = tt >> 3, seg = tt & 7;
                fx4 vv = *reinterpret_cast<const fx4*>(A + (size_t)(m0 + row) * K + k0 + seg * 4);
                s4 w; w[0] = f2b(vv[0]); w[1] = f2b(vv[1]); w[2] = f2b(vv[2]); w[3] = f2b(vv[3]);
                *reinterpret_cast<s4*>(&As[row * 40 + seg * 4]) = w;
            }
            {
                int row = tid >> 2, seg = tid & 3;
                s8 vb = *reinterpret_cast<const s8*>(Bt + (size_t)(n0 + row) * K + k0 + seg * 8);
                *reinterpret_cast<s8*>(&Bs[row * 40 + seg * 8]) = vb;
            }
            __syncthreads();
            s8 af[4], bfr[2];
#pragma unroll
            for (int mf = 0; mf < 4; ++mf)
                af[mf] = *reinterpret_cast<s8*>(&As[(wm * 64 + mf * 16 + lr) * 40 + lh * 8]);
#pragma unroll
            for (int nf = 0; nf < 2; ++nf)
                bfr[nf] = *reinterpret_cast<s8*>(&Bs[(wn * 32 + nf * 16 + lr) * 40 + lh * 8]);
#pragma unroll
            for (int mf = 0; mf < 4; ++mf)
#pragma unroll
                for (int nf = 0; nf < 2; ++nf)
                    acc[mf][nf] = __builtin_amdgcn_mfma_f32_16x16x32_bf16(af[mf], bfr[nf], acc[mf][nf], 0, 0, 0);
            __syncthreads();
        }
        short* fps = fpout + (size_t)s * MTOT * 320;
#pragma unroll
        for (int nf = 0; nf < 2; ++nf) {
            int col = n0 + wn * 32 + nf * 16 + lr;
            float bv = bias[col];
#pragma unroll
            for (int mf = 0; mf < 4; ++mf) {
                int r0 = m0 + wm * 64 + mf * 16 + lh * 4;
#pragma unroll
                for (int rg = 0; rg < 4; ++rg) {
                    float c = acc[mf][nf][rg] + bv;
                    fps[(size_t)(r0 + rg) * 320 + col] = f2b(c);
                    gacc[mf][nf][rg] += c;
                }
            }
        }
    }
#pragma unroll
    for (int nf = 0; nf < 2; ++nf) {
        int col = n0 + wn * 32 + nf * 16 + lr;
#pragma unroll
        for (int mf = 0; mf < 4; ++mf) {
            int r0 = m0 + wm * 64 + mf * 16 + lh * 4;
#pragma unroll
            for (int rg = 0; rg < 4; ++rg) {
                float g = gacc[mf][nf][rg] * (1.0f / 3.0f);
                attn_in[(size_t)(r0 + rg) * 480 + col] = f2b(g);
                gf32[(size_t)(r0 + rg) * 320 + col] = g;
            }
        }
    }
}

// ---------------------------------------------------------------------------
// Generic bf16-MFMA GEMM: C = act(A @ B + bias) [+ Af]. M fixed 16384.
// A: f32 (converted) or bf16, [M][lda]. Bt: [N][K] bf16. BM=128,BN=64,BK=32.
// ---------------------------------------------------------------------------
template<bool AF32, bool RELU, bool NMASK, bool ADDF, bool OUTF, bool OUTB>
__global__ __launch_bounds__(256) void gemm_k(
    const void* __restrict__ Ap, int lda,
    const short* __restrict__ Bt,
    const float* __restrict__ bias,
    float* __restrict__ Cf, int ldcf,
    short* __restrict__ Cb, int ldcb, int cboff,
    const float* __restrict__ Af, int ldaf,
    int N, int K, int ntiles)
{
    __shared__ short As[128 * 40];
    __shared__ short Bs[64 * 40];
    int bid = blockIdx.x;
    int mt = bid / ntiles, nt = bid - mt * ntiles;
    int m0 = mt * 128, n0 = nt * 64;
    int tid = threadIdx.x, l = tid & 63, wid = tid >> 6;
    int wm = wid & 1, wn = wid >> 1, lr = l & 15, lh = l >> 4;
    fx4 acc[4][2] = {};

    int nsteps = K >> 5;
    for (int kt = 0; kt < nsteps; ++kt) {
        int k0 = kt << 5;
        if constexpr (AF32) {
            const float* A = (const float*)Ap;
#pragma unroll
            for (int it = 0; it < 4; ++it) {
                int tt = tid + it * 256;
                int row = tt >> 3, seg = tt & 7;
                fx4 vv = *reinterpret_cast<const fx4*>(A + (size_t)(m0 + row) * lda + k0 + seg * 4);
                s4 w; w[0] = f2b(vv[0]); w[1] = f2b(vv[1]); w[2] = f2b(vv[2]); w[3] = f2b(vv[3]);
                *reinterpret_cast<s4*>(&As[row * 40 + seg * 4]) = w;
            }
        } else {
            const short* A = (const short*)Ap;
#pragma unroll
            for (int it = 0; it < 2; ++it) {
                int tt = tid + it * 256;
                int row = tt >> 2, seg = tt & 3;
                s8 vv = *reinterpret_cast<const s8*>(A + (size_t)(m0 + row) * lda + k0 + seg * 8);
                *reinterpret_cast<s8*>(&As[row * 40 + seg * 8]) = vv;
            }
        }
        {
            int row = tid >> 2, seg = tid & 3;
            s8 vb = {0, 0, 0, 0, 0, 0, 0, 0};
            if (!NMASK || (n0 + row) < N)
                vb = *reinterpret_cast<const s8*>(Bt + (size_t)(n0 + row) * K + k0 + seg * 8);
            *reinterpret_cast<s8*>(&Bs[row * 40 + seg * 8]) = vb;
        }
        __syncthreads();
        s8 af[4], bfr[2];
#pragma unroll
        for (int mf = 0; mf < 4; ++mf)
            af[mf] = *reinterpret_cast<s8*>(&As[(wm * 64 + mf * 16 + lr) * 40 + lh * 8]);
#pragma unroll
        for (int nf = 0; nf < 2; ++nf)
            bfr[nf] = *reinterpret_cast<s8*>(&Bs[(wn * 32 + nf * 16 + lr) * 40 + lh * 8]);
#pragma unroll
        for (int mf = 0; mf < 4; ++mf)
#pragma unroll
            for (int nf = 0; nf < 2; ++nf)
                acc[mf][nf] = __builtin_amdgcn_mfma_f32_16x16x32_bf16(af[mf], bfr[nf], acc[mf][nf], 0, 0, 0);
        __syncthreads();
    }

#pragma unroll
    for (int nf = 0; nf < 2; ++nf) {
        int col = n0 + wn * 32 + nf * 16 + lr;
        if (NMASK && col >= N) continue;
        float bv = bias[col];
#pragma unroll
        for (int mf = 0; mf < 4; ++mf) {
            int r0 = m0 + wm * 64 + mf * 16 + lh * 4;
#pragma unroll
            for (int rg = 0; rg < 4; ++rg) {
                float c = acc[mf][nf][rg] + bv;
                if (RELU) c = fmaxf(c, 0.0f);
                int row = r0 + rg;
                if constexpr (ADDF) c += Af[(size_t)row * ldaf + col];
                if constexpr (OUTF) Cf[(size_t)row * ldcf + col] = c;
                if constexpr (OUTB) Cb[(size_t)row * ldcb + cboff + col] = f2b(c);
            }
        }
    }
}

// ---------------------------------------------------------------------------
// attn logits (a1 @ Wa2 + ba2) -> softmax3 -> write attn; fused = sum_s w_s*fp_s
// One thread per point. grid = 64 x 256.
// ---------------------------------------------------------------------------
__global__ __launch_bounds__(256) void attn_fuse_kernel(
    const short* __restrict__ a1, const float* __restrict__ Wa2,
    const float* __restrict__ ba2, const short* __restrict__ fp,
    float* __restrict__ attn_out, short* __restrict__ fused)
{
    __shared__ float w2[320 * 3];
    int tid = threadIdx.x;
    if (tid < 240)
        *reinterpret_cast<fx4*>(&w2[tid * 4]) = *reinterpret_cast<const fx4*>(&Wa2[tid * 4]);
    __syncthreads();

    int i = blockIdx.x * 256 + tid;
    float acc0 = ba2[0], acc1 = ba2[1], acc2 = ba2[2];
    const short* arow = a1 + (size_t)i * 320;
    for (int kc = 0; kc < 320; kc += 8) {
        s8 v = *reinterpret_cast<const s8*>(arow + kc);
#pragma unroll
        for (int u = 0; u < 8; ++u) {
            float f = b2f(v[u]);
            int k = kc + u;
            acc0 = fmaf(f, w2[k * 3 + 0], acc0);
            acc1 = fmaf(f, w2[k * 3 + 1], acc1);
            acc2 = fmaf(f, w2[k * 3 + 2], acc2);
        }
    }
    float m = fmaxf(acc0, fmaxf(acc1, acc2));
    float e0 = expf(acc0 - m), e1 = expf(acc1 - m), e2 = expf(acc2 - m);
    float inv = 1.0f / (e0 + e1 + e2);
    float w0 = e0 * inv, w1 = e1 * inv, wc2 = e2 * inv;
    attn_out[(size_t)i * 3 + 0] = w0;
    attn_out[(size_t)i * 3 + 1] = w1;
    attn_out[(size_t)i * 3 + 2] = wc2;

    const short* r0 = fp + (size_t)i * 320;
    const short* r1 = r0 + (size_t)MTOT * 320;
    const short* r2 = r1 + (size_t)MTOT * 320;
    short* fo = fused + (size_t)i * 320;
    for (int kc = 0; kc < 320; kc += 8) {
        s8 v0 = *reinterpret_cast<const s8*>(r0 + kc);
        s8 v1 = *reinterpret_cast<const s8*>(r1 + kc);
        s8 v2 = *reinterpret_cast<const s8*>(r2 + kc);
        s8 o;
#pragma unroll
        for (int u = 0; u < 8; ++u) {
            float f = fmaf(w0, b2f(v0[u]), fmaf(w1, b2f(v1[u]), wc2 * b2f(v2[u])));
            o[u] = f2b(f);
        }
        *reinterpret_cast<s8*>(fo + kc) = o;
    }
}

// ---------------------------------------------------------------------------
extern "C" void kernel_launch(void* const* d_in, const int* in_sizes, int n_in,
                              void* d_out, int out_size, void* d_ws, size_t ws_size,
                              hipStream_t stream)
{
    const float* feat0  = (const float*)d_in[0];
    const float* feat1  = (const float*)d_in[1];
    const float* feat2  = (const float*)d_in[2];
    const float* logits = (const float*)d_in[3];
    const int*   labels = (const int*)d_in[4];
    const float* pos    = (const float*)d_in[5];
    const float* Wp0 = (const float*)d_in[6];   const float* bp0 = (const float*)d_in[7];
    const float* Wp1 = (const float*)d_in[8];   const float* bp1 = (const float*)d_in[9];
    const float* Wp2 = (const float*)d_in[10];  const float* bp2 = (const float*)d_in[11];
    const float* Wbe1 = (const float*)d_in[12]; const float* bbe1 = (const float*)d_in[13];
    const float* Wbe2 = (const float*)d_in[14]; const float* bbe2 = (const float*)d_in[15];
    const float* Wa1 = (const float*)d_in[16];  const float* ba1 = (const float*)d_in[17];
    const float* Wa2 = (const float*)d_in[18];  const float* ba2 = (const float*)d_in[19];
    const float* Wo1 = (const float*)d_in[20];  const float* bo1 = (const float*)d_in[21];
    const float* Wo2 = (const float*)d_in[22];  const float* bo2 = (const float*)d_in[23];

    char* p = (char*)d_ws;
    auto alloc = [&](size_t bytes) { char* r = p; p += (bytes + 255) & ~(size_t)255; return r; };
    short* bt_p0  = (short*)alloc((size_t)320 * 256 * 2);
    short* bt_p1  = (short*)alloc((size_t)320 * 512 * 2);
    short* bt_p2  = (short*)alloc((size_t)320 * 768 * 2);
    short* bt_be1 = (short*)alloc((size_t)96 * 32 * 2);
    short* bt_be2 = (short*)alloc((size_t)160 * 96 * 2);
    short* bt_a1  = (short*)alloc((size_t)320 * 480 * 2);
    short* bt_o1  = (short*)alloc((size_t)320 * 320 * 2);
    short* bt_o2  = (short*)alloc((size_t)320 * 320 * 2);
    float* info32 = (float*)alloc((size_t)MTOT * 32 * 4);
    short* h1     = (short*)alloc((size_t)MTOT * 96 * 2);
    short* attn_in= (short*)alloc((size_t)MTOT * 480 * 2);
    short* fpb    = (short*)alloc((size_t)3 * MTOT * 320 * 2);
    float* gf32   = (float*)alloc((size_t)MTOT * 320 * 4);
    short* a1b    = (short*)alloc((size_t)MTOT * 320 * 2);
    short* fusedb = (short*)alloc((size_t)MTOT * 320 * 2);
    short* hb     = (short*)alloc((size_t)MTOT * 320 * 2);

    float* outf = (float*)d_out;
    float* attn_out = outf + (size_t)MTOT * 320;

    auto WT = [&](const float* W, short* Bt, int K, int N, int Kp) {
        int tot = N * Kp;
        wtrans_kernel<<<(tot + 255) / 256, 256, 0, stream>>>(W, Bt, K, N, Kp);
    };
    WT(Wp0, bt_p0, 256, 320, 256);
    WT(Wp1, bt_p1, 512, 320, 512);
    WT(Wp2, bt_p2, 768, 320, 768);
    WT(Wbe1, bt_be1, 6, 96, 32);
    WT(Wbe2, bt_be2, 96, 160, 96);
    WT(Wa1, bt_a1, 480, 320, 480);
    WT(Wo1, bt_o1, 320, 320, 320);
    WT(Wo2, bt_o2, 320, 320, 320);

    knn_kernel<<<256, 256, 0, stream>>>(pos, labels, logits, info32);

    proj_kernel<<<640, 256, 0, stream>>>(feat0, feat1, feat2,
                                         bt_p0, bt_p1, bt_p2,
                                         bp0, bp1, bp2,
                                         fpb, attn_in, gf32);

    // info -> h1 (relu), N=96, K=32
    gemm_k<true, true, true, false, false, true><<<256, 256, 0, stream>>>(
        info32, 32, bt_be1, bbe1, nullptr, 0, h1, 96, 0, nullptr, 0, 96, 32, 2);
    // h1 -> enc (relu) into attn_in cols 320..479, N=160, K=96
    gemm_k<false, true, true, false, false, true><<<384, 256, 0, stream>>>(
        h1, 96, bt_be2, bbe2, nullptr, 0, attn_in, 480, 320, nullptr, 0, 160, 96, 3);
    // attn_in -> a1 (relu), N=320, K=480
    gemm_k<false, true, false, false, false, true><<<640, 256, 0, stream>>>(
        attn_in, 480, bt_a1, ba1, nullptr, 0, a1b, 320, 0, nullptr, 0, 320, 480, 5);

    attn_fuse_kernel<<<64, 256, 0, stream>>>(a1b, Wa2, ba2, fpb, attn_out, fusedb);

    // fused -> h (relu), N=320, K=320
    gemm_k<false, true, false, false, false, true><<<640, 256, 0, stream>>>(
        fusedb, 320, bt_o1, bo1, nullptr, 0, hb, 320, 0, nullptr, 0, 320, 320, 5);
    // h -> out (+global residual), f32 to d_out
    gemm_k<false, false, false, true, true, false><<<640, 256, 0, stream>>>(
        hb, 320, bt_o2, bo2, outf, 320, nullptr, 0, 0, gf32, 320, 320, 320, 5);
}

// Round 2
// 426.347 us; speedup vs baseline: 1.4485x; 1.4485x over previous
//
#include <hip/hip_runtime.h>
#include <stdint.h>

typedef float fx4 __attribute__((ext_vector_type(4)));
typedef short s8 __attribute__((ext_vector_type(8)));
typedef short s4 __attribute__((ext_vector_type(4)));

#define MTOT 16384
#define NPTS 4096

__device__ __forceinline__ float b2f(short s) {
    return __uint_as_float(((unsigned)(unsigned short)s) << 16);
}
__device__ __forceinline__ short f2b(float f) {
    unsigned u = __float_as_uint(f);
    u += 0x7fffu + ((u >> 16) & 1u);
    return (short)(u >> 16);
}

// ---------------------------------------------------------------------------
// Fused weight transpose + bf16 convert for all 8 weight matrices.
// W[K][N] f32 -> Bt[N][Kp] bf16 (zero pad K..Kp)
// ---------------------------------------------------------------------------
struct WTDesc {
    const float* W[8];
    short* Bt[8];
    int K[8];
    int N[8];
    int Kp[8];
    int base[9];
};

__global__ __launch_bounds__(256) void wtrans8_kernel(WTDesc d)
{
    int idx = blockIdx.x * 256 + threadIdx.x;
    if (idx >= d.base[8]) return;
    int s = 0;
#pragma unroll
    for (int t = 1; t < 8; ++t) if (idx >= d.base[t]) s = t;
    int local = idx - d.base[s];
    int Kp = d.Kp[s], K = d.K[s], N = d.N[s];
    int n = local / Kp, k = local - n * Kp;
    d.Bt[s][local] = (k < K) ? f2b(d.W[s][(size_t)k * N + n]) : (short)0;
}

// ---------------------------------------------------------------------------
// kNN + boundary info.
// grid = 512 blocks (4 batches x 128 chunks of 32 points), 512 threads.
// 16 threads/point, each scans a 256-point segment keeping sorted top-12 as
// packed u64 keys (d2bits<<32 | j<<4 | q). Merge: 12 rounds of 16-lane
// shfl-min extraction. LDS 54,272 B -> 3 blocks/CU.
// ---------------------------------------------------------------------------
__global__ __launch_bounds__(512, 6) void knn_kernel(
    const float* __restrict__ pos, const int* __restrict__ labels,
    const float* __restrict__ logits, float* __restrict__ info32)
{
    __shared__ alignas(16) char smem[54272];
    float* xs = (float*)smem;                       // 16 segs * 260 floats
    float* ys = xs + 4160;
    float* zs = ys + 4160;
    unsigned char* labs = (unsigned char*)(zs + 4160);  // 4096 B @49920
    float* sm_conf = (float*)(smem + 54016);        // 32 floats
    float* sm_ent  = sm_conf + 32;                  // 32 floats
    uint64_t* kd = (uint64_t*)smem;                 // alias xs/ys/zs: 6144 u64

    int b  = blockIdx.x >> 7;
    int pc = blockIdx.x & 127;
    int tid = threadIdx.x;

    for (int idx = tid; idx < NPTS; idx += 512) {
        int seg = idx >> 8, o = idx & 255;
        const float* pp = pos + (size_t)(b * NPTS + idx) * 3;
        xs[seg * 260 + o] = pp[0];
        ys[seg * 260 + o] = pp[1];
        zs[seg * 260 + o] = pp[2];
        labs[idx] = (unsigned char)labels[b * NPTS + idx];
    }
    __syncthreads();

    // softmax(logits/0.75) prepass: conf, entropy for the block's 32 points
    if (tid < 32) {
        int gi = pc * 32 + tid;
        const float* lg = logits + (size_t)(b * NPTS + gi) * 17;
        float v[17];
        float vmax = -3.0e38f;
#pragma unroll
        for (int c = 0; c < 17; ++c) { v[c] = lg[c] * (1.0f / 0.75f); vmax = fmaxf(vmax, v[c]); }
        float ssum = 0.f;
#pragma unroll
        for (int c = 0; c < 17; ++c) { v[c] = expf(v[c] - vmax); ssum += v[c]; }
        float inv = 1.0f / ssum;
        float conf = 0.f, ent = 0.f;
#pragma unroll
        for (int c = 0; c < 17; ++c) {
            float pprob = v[c] * inv;
            conf = fmaxf(conf, pprob);
            ent += pprob * logf(pprob + 1e-8f);
        }
        sm_conf[tid] = conf;
        sm_ent[tid] = -ent * (1.0f / 2.8332133f);   // / ln(17)
    }

    int lp = tid >> 4, q = tid & 15;
    int gi = pc * 32 + lp;
    int qi = gi >> 8, oi = gi & 255;
    float mx = xs[qi * 260 + oi], my = ys[qi * 260 + oi], mz = zs[qi * 260 + oi];
    int mylab = (int)labs[gi];

    uint64_t hk[12];
#pragma unroll
    for (int k = 0; k < 12; ++k) hk[k] = ~0ull;

    const float* xsq = xs + q * 260;
    const float* ysq = ys + q * 260;
    const float* zsq = zs + q * 260;
    int jbase = q * 256;
    uint32_t lobase = (uint32_t)((jbase << 4) | q);

    for (int jj = 0; jj < 256; jj += 4) {
        fx4 xv = *reinterpret_cast<const fx4*>(xsq + jj);
        fx4 yv = *reinterpret_cast<const fx4*>(ysq + jj);
        fx4 zv = *reinterpret_cast<const fx4*>(zsq + jj);
#pragma unroll
        for (int u = 0; u < 4; ++u) {
            float dx = xv[u] - mx, dy = yv[u] - my, dz = zv[u] - mz;
            float d2 = fmaf(dx, dx, fmaf(dy, dy, dz * dz));
            int j = jbase + jj + u;
            if (j == gi) d2 = 3.0e38f;
            uint64_t key = ((uint64_t)__float_as_uint(d2) << 32) |
                           (uint64_t)(lobase + (uint32_t)((jj + u) << 4));
            if (key < hk[11]) {
                hk[11] = key;
#pragma unroll
                for (int k = 11; k >= 1; --k) {
                    uint64_t a = hk[k], bb = hk[k - 1];
                    if (a < bb) { hk[k] = bb; hk[k - 1] = a; }
                }
            }
        }
    }

    __syncthreads();   // all position reads done; safe to alias kd over xs/ys/zs
    uint64_t* myl = kd + (lp * 192 + q * 12);
#pragma unroll
    for (int r = 0; r < 12; ++r) myl[r] = hk[r];
    __syncthreads();

    // 12 rounds of 16-lane min-extraction over the 16 sorted lists
    int ptr = 0;
    uint64_t head = myl[0];
    float sum_d = 0.f, sum_d2 = 0.f, sum_diff = 0.f, same_d = 0.f, bmin = 3.0e38f;
#pragma unroll 1
    for (int r = 0; r < 12; ++r) {
        uint64_t m = head;
#pragma unroll
        for (int s = 8; s >= 1; s >>= 1) {
            uint64_t o = (uint64_t)__shfl_xor((unsigned long long)m, s, 16);
            m = (o < m) ? o : m;
        }
        if (m == head) {
            ++ptr;
            head = (ptr < 12) ? myl[ptr] : ~0ull;
        }
        float d = sqrtf(__uint_as_float((uint32_t)(m >> 32)));
        int j = (int)((m >> 4) & 0xFFF);
        float isdiff = ((int)labs[j] != mylab) ? 1.0f : 0.0f;
        sum_d += d;
        sum_d2 = fmaf(d, d, sum_d2);
        sum_diff += isdiff;
        same_d = fmaf(d, 1.0f - isdiff, same_d);
        if (isdiff > 0.f) bmin = fminf(bmin, d);
    }

    if (q == 0) {
        float nsame = 12.0f - sum_diff;
        float mean_d = sum_d * (1.0f / 12.0f);
        float var = fmaxf(0.f, (sum_d2 - 12.0f * mean_d * mean_d) * (1.0f / 11.0f));
        float md_eps = mean_d + 1e-6f;
        float curvature = sqrtf(var) / md_eps;
        float density = 1.0f / md_eps;
        float same_dist = same_d / (nsame + 1e-6f);
        float bdist = (bmin < 2.9e38f) ? bmin : same_dist;
        float bscore = sum_diff * (1.0f / 12.0f);

        float* op = info32 + (size_t)(b * NPTS + gi) * 32;
        fx4 o0 = {bscore, sm_conf[lp], sm_ent[lp], density};
        fx4 o1 = {curvature, bdist, 0.f, 0.f};
        fx4 zz = {0.f, 0.f, 0.f, 0.f};
        *reinterpret_cast<fx4*>(op + 0)  = o0;
        *reinterpret_cast<fx4*>(op + 4)  = o1;
        *reinterpret_cast<fx4*>(op + 8)  = zz;
        *reinterpret_cast<fx4*>(op + 12) = zz;
        *reinterpret_cast<fx4*>(op + 16) = zz;
        *reinterpret_cast<fx4*>(op + 20) = zz;
        *reinterpret_cast<fx4*>(op + 24) = zz;
        *reinterpret_cast<fx4*>(op + 28) = zz;
    }
}

// ---------------------------------------------------------------------------
// Fused 3-scale projection: fp_s = feat_s @ Wp_s + bp_s (bf16 out),
// global = mean_s fp_s (bf16 into attn_in cols 0..319, f32 into gf32).
// BM=128, BN=64, BK=32, 4 waves (2x2), grid = 128*5.
// ---------------------------------------------------------------------------
__global__ __launch_bounds__(256) void proj_kernel(
    const float* __restrict__ f0, const float* __restrict__ f1, const float* __restrict__ f2,
    const short* __restrict__ bt0, const short* __restrict__ bt1, const short* __restrict__ bt2,
    const float* __restrict__ bp0, const float* __restrict__ bp1, const float* __restrict__ bp2,
    short* __restrict__ fpout, short* __restrict__ attn_in, float* __restrict__ gf32)
{
    __shared__ short As[128 * 40];
    __shared__ short Bs[64 * 40];
    int bid = blockIdx.x;
    int mt = bid / 5, nt = bid % 5;
    int m0 = mt * 128, n0 = nt * 64;
    int tid = threadIdx.x, l = tid & 63, wid = tid >> 6;
    int wm = wid & 1, wn = wid >> 1, lr = l & 15, lh = l >> 4;
    fx4 gacc[4][2] = {};

    for (int s = 0; s < 3; ++s) {
        const float* A = (s == 0) ? f0 : (s == 1 ? f1 : f2);
        const short* Bt = (s == 0) ? bt0 : (s == 1 ? bt1 : bt2);
        const float* bias = (s == 0) ? bp0 : (s == 1 ? bp1 : bp2);
        int K = (s == 0) ? 256 : (s == 1 ? 512 : 768);
        fx4 acc[4][2] = {};
        int nsteps = K >> 5;
        for (int kt = 0; kt < nsteps; ++kt) {
            int k0 = kt << 5;
#pragma unroll
            for (int it = 0; it < 4; ++it) {
                int tt = tid + it * 256;
                int row = tt >> 3, seg = tt & 7;
                fx4 vv = *reinterpret_cast<const fx4*>(A + (size_t)(m0 + row) * K + k0 + seg * 4);
                s4 w; w[0] = f2b(vv[0]); w[1] = f2b(vv[1]); w[2] = f2b(vv[2]); w[3] = f2b(vv[3]);
                *reinterpret_cast<s4*>(&As[row * 40 + seg * 4]) = w;
            }
            {
                int row = tid >> 2, seg = tid & 3;
                s8 vb = *reinterpret_cast<const s8*>(Bt + (size_t)(n0 + row) * K + k0 + seg * 8);
                *reinterpret_cast<s8*>(&Bs[row * 40 + seg * 8]) = vb;
            }
            __syncthreads();
            s8 af[4], bfr[2];
#pragma unroll
            for (int mf = 0; mf < 4; ++mf)
                af[mf] = *reinterpret_cast<s8*>(&As[(wm * 64 + mf * 16 + lr) * 40 + lh * 8]);
#pragma unroll
            for (int nf = 0; nf < 2; ++nf)
                bfr[nf] = *reinterpret_cast<s8*>(&Bs[(wn * 32 + nf * 16 + lr) * 40 + lh * 8]);
#pragma unroll
            for (int mf = 0; mf < 4; ++mf)
#pragma unroll
                for (int nf = 0; nf < 2; ++nf)
                    acc[mf][nf] = __builtin_amdgcn_mfma_f32_16x16x32_bf16(af[mf], bfr[nf], acc[mf][nf], 0, 0, 0);
            __syncthreads();
        }
        short* fps = fpout + (size_t)s * MTOT * 320;
#pragma unroll
        for (int nf = 0; nf < 2; ++nf) {
            int col = n0 + wn * 32 + nf * 16 + lr;
            float bv = bias[col];
#pragma unroll
            for (int mf = 0; mf < 4; ++mf) {
                int r0 = m0 + wm * 64 + mf * 16 + lh * 4;
#pragma unroll
                for (int rg = 0; rg < 4; ++rg) {
                    float c = acc[mf][nf][rg] + bv;
                    fps[(size_t)(r0 + rg) * 320 + col] = f2b(c);
                    gacc[mf][nf][rg] += c;
                }
            }
        }
    }
#pragma unroll
    for (int nf = 0; nf < 2; ++nf) {
        int col = n0 + wn * 32 + nf * 16 + lr;
#pragma unroll
        for (int mf = 0; mf < 4; ++mf) {
            int r0 = m0 + wm * 64 + mf * 16 + lh * 4;
#pragma unroll
            for (int rg = 0; rg < 4; ++rg) {
                float g = gacc[mf][nf][rg] * (1.0f / 3.0f);
                attn_in[(size_t)(r0 + rg) * 480 + col] = f2b(g);
                gf32[(size_t)(r0 + rg) * 320 + col] = g;
            }
        }
    }
}

// ---------------------------------------------------------------------------
// Generic bf16-MFMA GEMM: C = act(A @ B + bias) [+ Af]. M fixed 16384.
// A: f32 (converted) or bf16, [M][lda]. Bt: [N][K] bf16. BM=128,BN=64,BK=32.
// ---------------------------------------------------------------------------
template<bool AF32, bool RELU, bool NMASK, bool ADDF, bool OUTF, bool OUTB>
__global__ __launch_bounds__(256) void gemm_k(
    const void* __restrict__ Ap, int lda,
    const short* __restrict__ Bt,
    const float* __restrict__ bias,
    float* __restrict__ Cf, int ldcf,
    short* __restrict__ Cb, int ldcb, int cboff,
    const float* __restrict__ Af, int ldaf,
    int N, int K, int ntiles)
{
    __shared__ short As[128 * 40];
    __shared__ short Bs[64 * 40];
    int bid = blockIdx.x;
    int mt = bid / ntiles, nt = bid - mt * ntiles;
    int m0 = mt * 128, n0 = nt * 64;
    int tid = threadIdx.x, l = tid & 63, wid = tid >> 6;
    int wm = wid & 1, wn = wid >> 1, lr = l & 15, lh = l >> 4;
    fx4 acc[4][2] = {};

    int nsteps = K >> 5;
    for (int kt = 0; kt < nsteps; ++kt) {
        int k0 = kt << 5;
        if constexpr (AF32) {
            const float* A = (const float*)Ap;
#pragma unroll
            for (int it = 0; it < 4; ++it) {
                int tt = tid + it * 256;
                int row = tt >> 3, seg = tt & 7;
                fx4 vv = *reinterpret_cast<const fx4*>(A + (size_t)(m0 + row) * lda + k0 + seg * 4);
                s4 w; w[0] = f2b(vv[0]); w[1] = f2b(vv[1]); w[2] = f2b(vv[2]); w[3] = f2b(vv[3]);
                *reinterpret_cast<s4*>(&As[row * 40 + seg * 4]) = w;
            }
        } else {
            const short* A = (const short*)Ap;
#pragma unroll
            for (int it = 0; it < 2; ++it) {
                int tt = tid + it * 256;
                int row = tt >> 2, seg = tt & 3;
                s8 vv = *reinterpret_cast<const s8*>(A + (size_t)(m0 + row) * lda + k0 + seg * 8);
                *reinterpret_cast<s8*>(&As[row * 40 + seg * 8]) = vv;
            }
        }
        {
            int row = tid >> 2, seg = tid & 3;
            s8 vb = {0, 0, 0, 0, 0, 0, 0, 0};
            if (!NMASK || (n0 + row) < N)
                vb = *reinterpret_cast<const s8*>(Bt + (size_t)(n0 + row) * K + k0 + seg * 8);
            *reinterpret_cast<s8*>(&Bs[row * 40 + seg * 8]) = vb;
        }
        __syncthreads();
        s8 af[4], bfr[2];
#pragma unroll
        for (int mf = 0; mf < 4; ++mf)
            af[mf] = *reinterpret_cast<s8*>(&As[(wm * 64 + mf * 16 + lr) * 40 + lh * 8]);
#pragma unroll
        for (int nf = 0; nf < 2; ++nf)
            bfr[nf] = *reinterpret_cast<s8*>(&Bs[(wn * 32 + nf * 16 + lr) * 40 + lh * 8]);
#pragma unroll
        for (int mf = 0; mf < 4; ++mf)
#pragma unroll
            for (int nf = 0; nf < 2; ++nf)
                acc[mf][nf] = __builtin_amdgcn_mfma_f32_16x16x32_bf16(af[mf], bfr[nf], acc[mf][nf], 0, 0, 0);
        __syncthreads();
    }

#pragma unroll
    for (int nf = 0; nf < 2; ++nf) {
        int col = n0 + wn * 32 + nf * 16 + lr;
        if (NMASK && col >= N) continue;
        float bv = bias[col];
#pragma unroll
        for (int mf = 0; mf < 4; ++mf) {
            int r0 = m0 + wm * 64 + mf * 16 + lh * 4;
#pragma unroll
            for (int rg = 0; rg < 4; ++rg) {
                float c = acc[mf][nf][rg] + bv;
                if (RELU) c = fmaxf(c, 0.0f);
                int row = r0 + rg;
                if constexpr (ADDF) c += Af[(size_t)row * ldaf + col];
                if constexpr (OUTF) Cf[(size_t)row * ldcf + col] = c;
                if constexpr (OUTB) Cb[(size_t)row * ldcb + cboff + col] = f2b(c);
            }
        }
    }
}

// ---------------------------------------------------------------------------
// attn logits (a1 @ Wa2 + ba2) -> softmax3 -> write attn; fused = sum_s w_s*fp_s
// ---------------------------------------------------------------------------
__global__ __launch_bounds__(256) void attn_fuse_kernel(
    const short* __restrict__ a1, const float* __restrict__ Wa2,
    const float* __restrict__ ba2, const short* __restrict__ fp,
    float* __restrict__ attn_out, short* __restrict__ fused)
{
    __shared__ float w2[320 * 3];
    int tid = threadIdx.x;
    if (tid < 240)
        *reinterpret_cast<fx4*>(&w2[tid * 4]) = *reinterpret_cast<const fx4*>(&Wa2[tid * 4]);
    __syncthreads();

    int i = blockIdx.x * 256 + tid;
    float acc0 = ba2[0], acc1 = ba2[1], acc2 = ba2[2];
    const short* arow = a1 + (size_t)i * 320;
    for (int kc = 0; kc < 320; kc += 8) {
        s8 v = *reinterpret_cast<const s8*>(arow + kc);
#pragma unroll
        for (int u = 0; u < 8; ++u) {
            float f = b2f(v[u]);
            int k = kc + u;
            acc0 = fmaf(f, w2[k * 3 + 0], acc0);
            acc1 = fmaf(f, w2[k * 3 + 1], acc1);
            acc2 = fmaf(f, w2[k * 3 + 2], acc2);
        }
    }
    float m = fmaxf(acc0, fmaxf(acc1, acc2));
    float e0 = expf(acc0 - m), e1 = expf(acc1 - m), e2 = expf(acc2 - m);
    float inv = 1.0f / (e0 + e1 + e2);
    float w0 = e0 * inv, w1 = e1 * inv, wc2 = e2 * inv;
    attn_out[(size_t)i * 3 + 0] = w0;
    attn_out[(size_t)i * 3 + 1] = w1;
    attn_out[(size_t)i * 3 + 2] = wc2;

    const short* r0 = fp + (size_t)i * 320;
    const short* r1 = r0 + (size_t)MTOT * 320;
    const short* r2 = r1 + (size_t)MTOT * 320;
    short* fo = fused + (size_t)i * 320;
    for (int kc = 0; kc < 320; kc += 8) {
        s8 v0 = *reinterpret_cast<const s8*>(r0 + kc);
        s8 v1 = *reinterpret_cast<const s8*>(r1 + kc);
        s8 v2 = *reinterpret_cast<const s8*>(r2 + kc);
        s8 o;
#pragma unroll
        for (int u = 0; u < 8; ++u) {
            float f = fmaf(w0, b2f(v0[u]), fmaf(w1, b2f(v1[u]), wc2 * b2f(v2[u])));
            o[u] = f2b(f);
        }
        *reinterpret_cast<s8*>(fo + kc) = o;
    }
}

// ---------------------------------------------------------------------------
extern "C" void kernel_launch(void* const* d_in, const int* in_sizes, int n_in,
                              void* d_out, int out_size, void* d_ws, size_t ws_size,
                              hipStream_t stream)
{
    const float* feat0  = (const float*)d_in[0];
    const float* feat1  = (const float*)d_in[1];
    const float* feat2  = (const float*)d_in[2];
    const float* logits = (const float*)d_in[3];
    const int*   labels = (const int*)d_in[4];
    const float* pos    = (const float*)d_in[5];
    const float* Wp0 = (const float*)d_in[6];   const float* bp0 = (const float*)d_in[7];
    const float* Wp1 = (const float*)d_in[8];   const float* bp1 = (const float*)d_in[9];
    const float* Wp2 = (const float*)d_in[10];  const float* bp2 = (const float*)d_in[11];
    const float* Wbe1 = (const float*)d_in[12]; const float* bbe1 = (const float*)d_in[13];
    const float* Wbe2 = (const float*)d_in[14]; const float* bbe2 = (const float*)d_in[15];
    const float* Wa1 = (const float*)d_in[16];  const float* ba1 = (const float*)d_in[17];
    const float* Wa2 = (const float*)d_in[18];  const float* ba2 = (const float*)d_in[19];
    const float* Wo1 = (const float*)d_in[20];  const float* bo1 = (const float*)d_in[21];
    const float* Wo2 = (const float*)d_in[22];  const float* bo2 = (const float*)d_in[23];

    char* p = (char*)d_ws;
    auto alloc = [&](size_t bytes) { char* r = p; p += (bytes + 255) & ~(size_t)255; return r; };
    short* bt_p0  = (short*)alloc((size_t)320 * 256 * 2);
    short* bt_p1  = (short*)alloc((size_t)320 * 512 * 2);
    short* bt_p2  = (short*)alloc((size_t)320 * 768 * 2);
    short* bt_be1 = (short*)alloc((size_t)96 * 32 * 2);
    short* bt_be2 = (short*)alloc((size_t)160 * 96 * 2);
    short* bt_a1  = (short*)alloc((size_t)320 * 480 * 2);
    short* bt_o1  = (short*)alloc((size_t)320 * 320 * 2);
    short* bt_o2  = (short*)alloc((size_t)320 * 320 * 2);
    float* info32 = (float*)alloc((size_t)MTOT * 32 * 4);
    short* h1     = (short*)alloc((size_t)MTOT * 96 * 2);
    short* attn_in= (short*)alloc((size_t)MTOT * 480 * 2);
    short* fpb    = (short*)alloc((size_t)3 * MTOT * 320 * 2);
    float* gf32   = (float*)alloc((size_t)MTOT * 320 * 4);
    short* a1b    = (short*)alloc((size_t)MTOT * 320 * 2);
    short* fusedb = (short*)alloc((size_t)MTOT * 320 * 2);
    short* hb     = (short*)alloc((size_t)MTOT * 320 * 2);

    float* outf = (float*)d_out;
    float* attn_out = outf + (size_t)MTOT * 320;

    WTDesc wd;
    const float* Ws[8] = {Wp0, Wp1, Wp2, Wbe1, Wbe2, Wa1, Wo1, Wo2};
    short* Bts[8] = {bt_p0, bt_p1, bt_p2, bt_be1, bt_be2, bt_a1, bt_o1, bt_o2};
    int Ks[8]  = {256, 512, 768, 6, 96, 480, 320, 320};
    int Ns[8]  = {320, 320, 320, 96, 160, 320, 320, 320};
    int Kps[8] = {256, 512, 768, 32, 96, 480, 320, 320};
    int acc = 0;
    for (int s = 0; s < 8; ++s) {
        wd.W[s] = Ws[s]; wd.Bt[s] = Bts[s];
        wd.K[s] = Ks[s]; wd.N[s] = Ns[s]; wd.Kp[s] = Kps[s];
        wd.base[s] = acc;
        acc += Ns[s] * Kps[s];
    }
    wd.base[8] = acc;
    wtrans8_kernel<<<(acc + 255) / 256, 256, 0, stream>>>(wd);

    knn_kernel<<<512, 512, 0, stream>>>(pos, labels, logits, info32);

    proj_kernel<<<640, 256, 0, stream>>>(feat0, feat1, feat2,
                                         bt_p0, bt_p1, bt_p2,
                                         bp0, bp1, bp2,
                                         fpb, attn_in, gf32);

    // info -> h1 (relu), N=96, K=32
    gemm_k<true, true, true, false, false, true><<<256, 256, 0, stream>>>(
        info32, 32, bt_be1, bbe1, nullptr, 0, h1, 96, 0, nullptr, 0, 96, 32, 2);
    // h1 -> enc (relu) into attn_in cols 320..479, N=160, K=96
    gemm_k<false, true, true, false, false, true><<<384, 256, 0, stream>>>(
        h1, 96, bt_be2, bbe2, nullptr, 0, attn_in, 480, 320, nullptr, 0, 160, 96, 3);
    // attn_in -> a1 (relu), N=320, K=480
    gemm_k<false, true, false, false, false, true><<<640, 256, 0, stream>>>(
        attn_in, 480, bt_a1, ba1, nullptr, 0, a1b, 320, 0, nullptr, 0, 320, 480, 5);

    attn_fuse_kernel<<<64, 256, 0, stream>>>(a1b, Wa2, ba2, fpb, attn_out, fusedb);

    // fused -> h (relu), N=320, K=320
    gemm_k<false, true, false, false, false, true><<<640, 256, 0, stream>>>(
        fusedb, 320, bt_o1, bo1, nullptr, 0, hb, 320, 0, nullptr, 0, 320, 320, 5);
    // h -> out (+global residual), f32 to d_out
    gemm_k<false, false, false, true, true, false><<<640, 256, 0, stream>>>(
        hb, 320, bt_o2, bo2, outf, 320, nullptr, 0, 0, gf32, 320, 320, 320, 5);
}

// Round 3
// 300.139 us; speedup vs baseline: 2.0576x; 1.4205x over previous
//
#include <hip/hip_runtime.h>
#include <stdint.h>

typedef float fx4 __attribute__((ext_vector_type(4)));
typedef short s8 __attribute__((ext_vector_type(8)));
typedef short s4 __attribute__((ext_vector_type(4)));
typedef unsigned int u32;
typedef u32 ux4 __attribute__((ext_vector_type(4)));

#define MTOT 16384
#define NPTS 4096

__device__ __forceinline__ float b2f(short s) {
    return __uint_as_float(((unsigned)(unsigned short)s) << 16);
}
__device__ __forceinline__ short f2b(float f) {
    unsigned u = __float_as_uint(f);
    u += 0x7fffu + ((u >> 16) & 1u);
    return (short)(u >> 16);
}

// ---------------------------------------------------------------------------
// Fused weight transpose + bf16 convert for all 8 weight matrices.
// ---------------------------------------------------------------------------
struct WTDesc {
    const float* W[8];
    short* Bt[8];
    int K[8];
    int N[8];
    int Kp[8];
    int base[9];
};

__global__ __launch_bounds__(256) void wtrans8_kernel(WTDesc d)
{
    int idx = blockIdx.x * 256 + threadIdx.x;
    if (idx >= d.base[8]) return;
    int s = 0;
#pragma unroll
    for (int t = 1; t < 8; ++t) if (idx >= d.base[t]) s = t;
    int local = idx - d.base[s];
    int Kp = d.Kp[s], K = d.K[s], N = d.N[s];
    int n = local / Kp, k = local - n * Kp;
    d.Bt[s][local] = (k < K) ? f2b(d.W[s][(size_t)k * N + n]) : (short)0;
}

// ---------------------------------------------------------------------------
// kNN part 1: per (batch, candidate-chunk of 1024, point-chunk of 64) find
// each point's top-12 within the chunk. Keys: (d2bits & 0xFFFFF000) | j.
// 512 threads = 64 points x 8 lanes; lane scans 128 candidates from LDS.
// Output: sorted 12-key list per (point, chunk).
// ---------------------------------------------------------------------------
#define SEGW 132   // 128 + 4: segment stagger -> distinct banks per lane group

__global__ __launch_bounds__(512) void knn_part_kernel(
    const float* __restrict__ pos, u32* __restrict__ keys)
{
    __shared__ float xs[8 * SEGW], ys[8 * SEGW], zs[8 * SEGW];  // 12,672 B
    int bid = blockIdx.x;
    int b   = bid >> 8;
    int cc  = (bid >> 6) & 3;
    int pch = bid & 63;
    int tid = threadIdx.x;
    int jb  = cc << 10;

    for (int idx = tid; idx < 1024; idx += 512) {
        int seg = idx >> 7, o = idx & 127;
        const float* pp = pos + (size_t)(b * NPTS + jb + idx) * 3;
        xs[seg * SEGW + o] = pp[0];
        ys[seg * SEGW + o] = pp[1];
        zs[seg * SEGW + o] = pp[2];
    }
    __syncthreads();

    int lp = tid >> 3, q = tid & 7;
    int gi = pch * 64 + lp;
    const float* mp = pos + (size_t)(b * NPTS + gi) * 3;
    float mx = mp[0], my = mp[1], mz = mp[2];

    u32 hk[12];
#pragma unroll
    for (int k = 0; k < 12; ++k) hk[k] = 0xFFFFFFFFu;

    const float* xsq = xs + q * SEGW;
    const float* ysq = ys + q * SEGW;
    const float* zsq = zs + q * SEGW;
    int jg0 = jb + q * 128;

    for (int jj = 0; jj < 128; jj += 4) {
        fx4 xv = *reinterpret_cast<const fx4*>(xsq + jj);
        fx4 yv = *reinterpret_cast<const fx4*>(ysq + jj);
        fx4 zv = *reinterpret_cast<const fx4*>(zsq + jj);
#pragma unroll
        for (int u = 0; u < 4; ++u) {
            float dx = xv[u] - mx, dy = yv[u] - my, dz = zv[u] - mz;
            float d2 = fmaf(dx, dx, fmaf(dy, dy, dz * dz));
            int jg = jg0 + jj + u;
            u32 key = (__float_as_uint(d2) & 0xFFFFF000u) | (u32)jg;
            if (jg == gi) key = 0xFFFFFFFFu;
            if (key < hk[11]) {
                hk[11] = key;
#pragma unroll
                for (int k = 11; k >= 1; --k) {
                    u32 a = hk[k], bb = hk[k - 1];
                    u32 mn = (a < bb) ? a : bb;
                    u32 mxv = (a < bb) ? bb : a;
                    hk[k - 1] = mn; hk[k] = mxv;
                }
            }
        }
    }

    // merge the 8 lanes' sorted 12-lists -> sorted top-12 for the point
    u32 out[12];
#pragma unroll
    for (int r = 0; r < 12; ++r) {
        u32 m = hk[0];
        u32 o1 = __shfl_xor(m, 4, 8); m = (o1 < m) ? o1 : m;
        u32 o2 = __shfl_xor(m, 2, 8); m = (o2 < m) ? o2 : m;
        u32 o3 = __shfl_xor(m, 1, 8); m = (o3 < m) ? o3 : m;
        if (m == hk[0]) {   // exactly one lane advances (keys unique)
#pragma unroll
            for (int k = 0; k < 11; ++k) hk[k] = hk[k + 1];
            hk[11] = 0xFFFFFFFFu;
        }
        out[r] = m;
    }

    size_t kb = ((size_t)(b * NPTS + gi) * 4 + cc) * 12;
    if (q == 0) *reinterpret_cast<ux4*>(&keys[kb])     = (ux4){out[0], out[1], out[2], out[3]};
    if (q == 1) *reinterpret_cast<ux4*>(&keys[kb + 4]) = (ux4){out[4], out[5], out[6], out[7]};
    if (q == 2) *reinterpret_cast<ux4*>(&keys[kb + 8]) = (ux4){out[8], out[9], out[10], out[11]};
}

// ---------------------------------------------------------------------------
// kNN part 2: merge 4 sorted 12-lists per point, compute boundary stats +
// logits softmax -> info32 (zero-padded to 32 cols).
// 256 blocks x 256 threads = 64 points/block, 4 lanes/point.
// ---------------------------------------------------------------------------
__global__ __launch_bounds__(256) void knn_merge_kernel(
    const u32* __restrict__ keys, const int* __restrict__ labels,
    const float* __restrict__ logits, float* __restrict__ info32)
{
    __shared__ unsigned char labs[NPTS];
    int b  = blockIdx.x >> 6;
    int pc = blockIdx.x & 63;
    int tid = threadIdx.x;
    for (int idx = tid; idx < NPTS; idx += 256)
        labs[idx] = (unsigned char)labels[b * NPTS + idx];
    __syncthreads();

    int lp = tid >> 2, q = tid & 3;
    int gi = pc * 64 + lp;
    size_t kb = ((size_t)(b * NPTS + gi) * 4 + q) * 12;
    ux4 k0 = *reinterpret_cast<const ux4*>(&keys[kb]);
    ux4 k1 = *reinterpret_cast<const ux4*>(&keys[kb + 4]);
    ux4 k2 = *reinterpret_cast<const ux4*>(&keys[kb + 8]);
    u32 hk[12];
    hk[0] = k0[0]; hk[1] = k0[1]; hk[2] = k0[2]; hk[3] = k0[3];
    hk[4] = k1[0]; hk[5] = k1[1]; hk[6] = k1[2]; hk[7] = k1[3];
    hk[8] = k2[0]; hk[9] = k2[1]; hk[10] = k2[2]; hk[11] = k2[3];

    int mylab = (int)labs[gi];
    float sum_d = 0.f, sum_d2 = 0.f, sum_diff = 0.f, same_d = 0.f, bmin = 3.0e38f;
#pragma unroll
    for (int r = 0; r < 12; ++r) {
        u32 m = hk[0];
        u32 o1 = __shfl_xor(m, 2, 4); m = (o1 < m) ? o1 : m;
        u32 o2 = __shfl_xor(m, 1, 4); m = (o2 < m) ? o2 : m;
        if (m == hk[0]) {
#pragma unroll
            for (int k = 0; k < 11; ++k) hk[k] = hk[k + 1];
            hk[11] = 0xFFFFFFFFu;
        }
        float d = sqrtf(__uint_as_float(m & 0xFFFFF000u));
        int j = (int)(m & 0xFFFu);
        float isdiff = ((int)labs[j] != mylab) ? 1.0f : 0.0f;
        sum_d += d;
        sum_d2 = fmaf(d, d, sum_d2);
        sum_diff += isdiff;
        same_d = fmaf(d, 1.0f - isdiff, same_d);
        if (isdiff > 0.f) bmin = fminf(bmin, d);
    }

    if (q == 0) {
        float nsame = 12.0f - sum_diff;
        float mean_d = sum_d * (1.0f / 12.0f);
        float var = fmaxf(0.f, (sum_d2 - 12.0f * mean_d * mean_d) * (1.0f / 11.0f));
        float md_eps = mean_d + 1e-6f;
        float curvature = sqrtf(var) / md_eps;
        float density = 1.0f / md_eps;
        float same_dist = same_d / (nsame + 1e-6f);
        float bdist = (bmin < 2.9e38f) ? bmin : same_dist;
        float bscore = sum_diff * (1.0f / 12.0f);

        const float* lg = logits + (size_t)(b * NPTS + gi) * 17;
        float v[17];
        float vmax = -3.0e38f;
#pragma unroll
        for (int c = 0; c < 17; ++c) { v[c] = lg[c] * (1.0f / 0.75f); vmax = fmaxf(vmax, v[c]); }
        float ssum = 0.f;
#pragma unroll
        for (int c = 0; c < 17; ++c) { v[c] = expf(v[c] - vmax); ssum += v[c]; }
        float inv = 1.0f / ssum;
        float conf = 0.f, ent = 0.f;
#pragma unroll
        for (int c = 0; c < 17; ++c) {
            float pprob = v[c] * inv;
            conf = fmaxf(conf, pprob);
            ent += pprob * logf(pprob + 1e-8f);
        }
        ent = -ent * (1.0f / 2.8332133f);  // / ln(17)

        float* op = info32 + (size_t)(b * NPTS + gi) * 32;
        fx4 o0 = {bscore, conf, ent, density};
        fx4 o1v = {curvature, bdist, 0.f, 0.f};
        fx4 zz = {0.f, 0.f, 0.f, 0.f};
        *reinterpret_cast<fx4*>(op + 0)  = o0;
        *reinterpret_cast<fx4*>(op + 4)  = o1v;
        *reinterpret_cast<fx4*>(op + 8)  = zz;
        *reinterpret_cast<fx4*>(op + 12) = zz;
        *reinterpret_cast<fx4*>(op + 16) = zz;
        *reinterpret_cast<fx4*>(op + 20) = zz;
        *reinterpret_cast<fx4*>(op + 24) = zz;
        *reinterpret_cast<fx4*>(op + 28) = zz;
    }
}

// ---------------------------------------------------------------------------
// Fused 3-scale projection: fp_s = feat_s @ Wp_s + bp_s (bf16 out),
// global = mean_s fp_s (bf16 into attn_in cols 0..319, f32 into gf32).
// ---------------------------------------------------------------------------
__global__ __launch_bounds__(256) void proj_kernel(
    const float* __restrict__ f0, const float* __restrict__ f1, const float* __restrict__ f2,
    const short* __restrict__ bt0, const short* __restrict__ bt1, const short* __restrict__ bt2,
    const float* __restrict__ bp0, const float* __restrict__ bp1, const float* __restrict__ bp2,
    short* __restrict__ fpout, short* __restrict__ attn_in, float* __restrict__ gf32)
{
    __shared__ short As[128 * 40];
    __shared__ short Bs[64 * 40];
    int bid = blockIdx.x;
    int mt = bid / 5, nt = bid % 5;
    int m0 = mt * 128, n0 = nt * 64;
    int tid = threadIdx.x, l = tid & 63, wid = tid >> 6;
    int wm = wid & 1, wn = wid >> 1, lr = l & 15, lh = l >> 4;
    fx4 gacc[4][2] = {};

    for (int s = 0; s < 3; ++s) {
        const float* A = (s == 0) ? f0 : (s == 1 ? f1 : f2);
        const short* Bt = (s == 0) ? bt0 : (s == 1 ? bt1 : bt2);
        const float* bias = (s == 0) ? bp0 : (s == 1 ? bp1 : bp2);
        int K = (s == 0) ? 256 : (s == 1 ? 512 : 768);
        fx4 acc[4][2] = {};
        int nsteps = K >> 5;
        for (int kt = 0; kt < nsteps; ++kt) {
            int k0 = kt << 5;
#pragma unroll
            for (int it = 0; it < 4; ++it) {
                int tt = tid + it * 256;
                int row = tt >> 3, seg = tt & 7;
                fx4 vv = *reinterpret_cast<const fx4*>(A + (size_t)(m0 + row) * K + k0 + seg * 4);
                s4 w; w[0] = f2b(vv[0]); w[1] = f2b(vv[1]); w[2] = f2b(vv[2]); w[3] = f2b(vv[3]);
                *reinterpret_cast<s4*>(&As[row * 40 + seg * 4]) = w;
            }
            {
                int row = tid >> 2, seg = tid & 3;
                s8 vb = *reinterpret_cast<const s8*>(Bt + (size_t)(n0 + row) * K + k0 + seg * 8);
                *reinterpret_cast<s8*>(&Bs[row * 40 + seg * 8]) = vb;
            }
            __syncthreads();
            s8 af[4], bfr[2];
#pragma unroll
            for (int mf = 0; mf < 4; ++mf)
                af[mf] = *reinterpret_cast<s8*>(&As[(wm * 64 + mf * 16 + lr) * 40 + lh * 8]);
#pragma unroll
            for (int nf = 0; nf < 2; ++nf)
                bfr[nf] = *reinterpret_cast<s8*>(&Bs[(wn * 32 + nf * 16 + lr) * 40 + lh * 8]);
#pragma unroll
            for (int mf = 0; mf < 4; ++mf)
#pragma unroll
                for (int nf = 0; nf < 2; ++nf)
                    acc[mf][nf] = __builtin_amdgcn_mfma_f32_16x16x32_bf16(af[mf], bfr[nf], acc[mf][nf], 0, 0, 0);
            __syncthreads();
        }
        short* fps = fpout + (size_t)s * MTOT * 320;
#pragma unroll
        for (int nf = 0; nf < 2; ++nf) {
            int col = n0 + wn * 32 + nf * 16 + lr;
            float bv = bias[col];
#pragma unroll
            for (int mf = 0; mf < 4; ++mf) {
                int r0 = m0 + wm * 64 + mf * 16 + lh * 4;
#pragma unroll
                for (int rg = 0; rg < 4; ++rg) {
                    float c = acc[mf][nf][rg] + bv;
                    fps[(size_t)(r0 + rg) * 320 + col] = f2b(c);
                    gacc[mf][nf][rg] += c;
                }
            }
        }
    }
#pragma unroll
    for (int nf = 0; nf < 2; ++nf) {
        int col = n0 + wn * 32 + nf * 16 + lr;
#pragma unroll
        for (int mf = 0; mf < 4; ++mf) {
            int r0 = m0 + wm * 64 + mf * 16 + lh * 4;
#pragma unroll
            for (int rg = 0; rg < 4; ++rg) {
                float g = gacc[mf][nf][rg] * (1.0f / 3.0f);
                attn_in[(size_t)(r0 + rg) * 480 + col] = f2b(g);
                gf32[(size_t)(r0 + rg) * 320 + col] = g;
            }
        }
    }
}

// ---------------------------------------------------------------------------
// Generic bf16-MFMA GEMM: C = act(A @ B + bias) [+ Af]. M fixed 16384.
// ---------------------------------------------------------------------------
template<bool AF32, bool RELU, bool NMASK, bool ADDF, bool OUTF, bool OUTB>
__global__ __launch_bounds__(256) void gemm_k(
    const void* __restrict__ Ap, int lda,
    const short* __restrict__ Bt,
    const float* __restrict__ bias,
    float* __restrict__ Cf, int ldcf,
    short* __restrict__ Cb, int ldcb, int cboff,
    const float* __restrict__ Af, int ldaf,
    int N, int K, int ntiles)
{
    __shared__ short As[128 * 40];
    __shared__ short Bs[64 * 40];
    int bid = blockIdx.x;
    int mt = bid / ntiles, nt = bid - mt * ntiles;
    int m0 = mt * 128, n0 = nt * 64;
    int tid = threadIdx.x, l = tid & 63, wid = tid >> 6;
    int wm = wid & 1, wn = wid >> 1, lr = l & 15, lh = l >> 4;
    fx4 acc[4][2] = {};

    int nsteps = K >> 5;
    for (int kt = 0; kt < nsteps; ++kt) {
        int k0 = kt << 5;
        if constexpr (AF32) {
            const float* A = (const float*)Ap;
#pragma unroll
            for (int it = 0; it < 4; ++it) {
                int tt = tid + it * 256;
                int row = tt >> 3, seg = tt & 7;
                fx4 vv = *reinterpret_cast<const fx4*>(A + (size_t)(m0 + row) * lda + k0 + seg * 4);
                s4 w; w[0] = f2b(vv[0]); w[1] = f2b(vv[1]); w[2] = f2b(vv[2]); w[3] = f2b(vv[3]);
                *reinterpret_cast<s4*>(&As[row * 40 + seg * 4]) = w;
            }
        } else {
            const short* A = (const short*)Ap;
#pragma unroll
            for (int it = 0; it < 2; ++it) {
                int tt = tid + it * 256;
                int row = tt >> 2, seg = tt & 3;
                s8 vv = *reinterpret_cast<const s8*>(A + (size_t)(m0 + row) * lda + k0 + seg * 8);
                *reinterpret_cast<s8*>(&As[row * 40 + seg * 8]) = vv;
            }
        }
        {
            int row = tid >> 2, seg = tid & 3;
            s8 vb = {0, 0, 0, 0, 0, 0, 0, 0};
            if (!NMASK || (n0 + row) < N)
                vb = *reinterpret_cast<const s8*>(Bt + (size_t)(n0 + row) * K + k0 + seg * 8);
            *reinterpret_cast<s8*>(&Bs[row * 40 + seg * 8]) = vb;
        }
        __syncthreads();
        s8 af[4], bfr[2];
#pragma unroll
        for (int mf = 0; mf < 4; ++mf)
            af[mf] = *reinterpret_cast<s8*>(&As[(wm * 64 + mf * 16 + lr) * 40 + lh * 8]);
#pragma unroll
        for (int nf = 0; nf < 2; ++nf)
            bfr[nf] = *reinterpret_cast<s8*>(&Bs[(wn * 32 + nf * 16 + lr) * 40 + lh * 8]);
#pragma unroll
        for (int mf = 0; mf < 4; ++mf)
#pragma unroll
            for (int nf = 0; nf < 2; ++nf)
                acc[mf][nf] = __builtin_amdgcn_mfma_f32_16x16x32_bf16(af[mf], bfr[nf], acc[mf][nf], 0, 0, 0);
        __syncthreads();
    }

#pragma unroll
    for (int nf = 0; nf < 2; ++nf) {
        int col = n0 + wn * 32 + nf * 16 + lr;
        if (NMASK && col >= N) continue;
        float bv = bias[col];
#pragma unroll
        for (int mf = 0; mf < 4; ++mf) {
            int r0 = m0 + wm * 64 + mf * 16 + lh * 4;
#pragma unroll
            for (int rg = 0; rg < 4; ++rg) {
                float c = acc[mf][nf][rg] + bv;
                if (RELU) c = fmaxf(c, 0.0f);
                int row = r0 + rg;
                if constexpr (ADDF) c += Af[(size_t)row * ldaf + col];
                if constexpr (OUTF) Cf[(size_t)row * ldcf + col] = c;
                if constexpr (OUTB) Cb[(size_t)row * ldcb + cboff + col] = f2b(c);
            }
        }
    }
}

// ---------------------------------------------------------------------------
// attn logits (a1 @ Wa2 + ba2) -> softmax3 -> write attn; fused = sum_s w_s*fp_s
// ---------------------------------------------------------------------------
__global__ __launch_bounds__(256) void attn_fuse_kernel(
    const short* __restrict__ a1, const float* __restrict__ Wa2,
    const float* __restrict__ ba2, const short* __restrict__ fp,
    float* __restrict__ attn_out, short* __restrict__ fused)
{
    __shared__ float w2[320 * 3];
    int tid = threadIdx.x;
    if (tid < 240)
        *reinterpret_cast<fx4*>(&w2[tid * 4]) = *reinterpret_cast<const fx4*>(&Wa2[tid * 4]);
    __syncthreads();

    int i = blockIdx.x * 256 + tid;
    float acc0 = ba2[0], acc1 = ba2[1], acc2 = ba2[2];
    const short* arow = a1 + (size_t)i * 320;
    for (int kc = 0; kc < 320; kc += 8) {
        s8 v = *reinterpret_cast<const s8*>(arow + kc);
#pragma unroll
        for (int u = 0; u < 8; ++u) {
            float f = b2f(v[u]);
            int k = kc + u;
            acc0 = fmaf(f, w2[k * 3 + 0], acc0);
            acc1 = fmaf(f, w2[k * 3 + 1], acc1);
            acc2 = fmaf(f, w2[k * 3 + 2], acc2);
        }
    }
    float m = fmaxf(acc0, fmaxf(acc1, acc2));
    float e0 = expf(acc0 - m), e1 = expf(acc1 - m), e2 = expf(acc2 - m);
    float inv = 1.0f / (e0 + e1 + e2);
    float w0 = e0 * inv, w1 = e1 * inv, wc2 = e2 * inv;
    attn_out[(size_t)i * 3 + 0] = w0;
    attn_out[(size_t)i * 3 + 1] = w1;
    attn_out[(size_t)i * 3 + 2] = wc2;

    const short* r0 = fp + (size_t)i * 320;
    const short* r1 = r0 + (size_t)MTOT * 320;
    const short* r2 = r1 + (size_t)MTOT * 320;
    short* fo = fused + (size_t)i * 320;
    for (int kc = 0; kc < 320; kc += 8) {
        s8 v0 = *reinterpret_cast<const s8*>(r0 + kc);
        s8 v1 = *reinterpret_cast<const s8*>(r1 + kc);
        s8 v2 = *reinterpret_cast<const s8*>(r2 + kc);
        s8 o;
#pragma unroll
        for (int u = 0; u < 8; ++u) {
            float f = fmaf(w0, b2f(v0[u]), fmaf(w1, b2f(v1[u]), wc2 * b2f(v2[u])));
            o[u] = f2b(f);
        }
        *reinterpret_cast<s8*>(fo + kc) = o;
    }
}

// ---------------------------------------------------------------------------
extern "C" void kernel_launch(void* const* d_in, const int* in_sizes, int n_in,
                              void* d_out, int out_size, void* d_ws, size_t ws_size,
                              hipStream_t stream)
{
    const float* feat0  = (const float*)d_in[0];
    const float* feat1  = (const float*)d_in[1];
    const float* feat2  = (const float*)d_in[2];
    const float* logits = (const float*)d_in[3];
    const int*   labels = (const int*)d_in[4];
    const float* pos    = (const float*)d_in[5];
    const float* Wp0 = (const float*)d_in[6];   const float* bp0 = (const float*)d_in[7];
    const float* Wp1 = (const float*)d_in[8];   const float* bp1 = (const float*)d_in[9];
    const float* Wp2 = (const float*)d_in[10];  const float* bp2 = (const float*)d_in[11];
    const float* Wbe1 = (const float*)d_in[12]; const float* bbe1 = (const float*)d_in[13];
    const float* Wbe2 = (const float*)d_in[14]; const float* bbe2 = (const float*)d_in[15];
    const float* Wa1 = (const float*)d_in[16];  const float* ba1 = (const float*)d_in[17];
    const float* Wa2 = (const float*)d_in[18];  const float* ba2 = (const float*)d_in[19];
    const float* Wo1 = (const float*)d_in[20];  const float* bo1 = (const float*)d_in[21];
    const float* Wo2 = (const float*)d_in[22];  const float* bo2 = (const float*)d_in[23];

    char* p = (char*)d_ws;
    auto alloc = [&](size_t bytes) { char* r = p; p += (bytes + 255) & ~(size_t)255; return r; };
    short* bt_p0  = (short*)alloc((size_t)320 * 256 * 2);
    short* bt_p1  = (short*)alloc((size_t)320 * 512 * 2);
    short* bt_p2  = (short*)alloc((size_t)320 * 768 * 2);
    short* bt_be1 = (short*)alloc((size_t)96 * 32 * 2);
    short* bt_be2 = (short*)alloc((size_t)160 * 96 * 2);
    short* bt_a1  = (short*)alloc((size_t)320 * 480 * 2);
    short* bt_o1  = (short*)alloc((size_t)320 * 320 * 2);
    short* bt_o2  = (short*)alloc((size_t)320 * 320 * 2);
    float* info32 = (float*)alloc((size_t)MTOT * 32 * 4);
    short* h1     = (short*)alloc((size_t)MTOT * 96 * 2);
    short* attn_in= (short*)alloc((size_t)MTOT * 480 * 2);
    short* fpb    = (short*)alloc((size_t)3 * MTOT * 320 * 2);
    float* gf32   = (float*)alloc((size_t)MTOT * 320 * 4);
    short* a1b    = (short*)alloc((size_t)MTOT * 320 * 2);
    short* fusedb = (short*)alloc((size_t)MTOT * 320 * 2);
    short* hb     = (short*)alloc((size_t)MTOT * 320 * 2);

    // knn keys (16384 * 4 * 12 u32 = 3.1 MB) alias hb: hb is only written at
    // dispatch "fused->h", long after knn_merge consumed keys.
    u32* knnkeys = (u32*)hb;

    float* outf = (float*)d_out;
    float* attn_out = outf + (size_t)MTOT * 320;

    WTDesc wd;
    const float* Ws[8] = {Wp0, Wp1, Wp2, Wbe1, Wbe2, Wa1, Wo1, Wo2};
    short* Bts[8] = {bt_p0, bt_p1, bt_p2, bt_be1, bt_be2, bt_a1, bt_o1, bt_o2};
    int Ks[8]  = {256, 512, 768, 6, 96, 480, 320, 320};
    int Ns[8]  = {320, 320, 320, 96, 160, 320, 320, 320};
    int Kps[8] = {256, 512, 768, 32, 96, 480, 320, 320};
    int acc = 0;
    for (int s = 0; s < 8; ++s) {
        wd.W[s] = Ws[s]; wd.Bt[s] = Bts[s];
        wd.K[s] = Ks[s]; wd.N[s] = Ns[s]; wd.Kp[s] = Kps[s];
        wd.base[s] = acc;
        acc += Ns[s] * Kps[s];
    }
    wd.base[8] = acc;
    wtrans8_kernel<<<(acc + 255) / 256, 256, 0, stream>>>(wd);

    knn_part_kernel<<<1024, 512, 0, stream>>>(pos, knnkeys);
    knn_merge_kernel<<<256, 256, 0, stream>>>(knnkeys, labels, logits, info32);

    proj_kernel<<<640, 256, 0, stream>>>(feat0, feat1, feat2,
                                         bt_p0, bt_p1, bt_p2,
                                         bp0, bp1, bp2,
                                         fpb, attn_in, gf32);

    // info -> h1 (relu), N=96, K=32
    gemm_k<true, true, true, false, false, true><<<256, 256, 0, stream>>>(
        info32, 32, bt_be1, bbe1, nullptr, 0, h1, 96, 0, nullptr, 0, 96, 32, 2);
    // h1 -> enc (relu) into attn_in cols 320..479, N=160, K=96
    gemm_k<false, true, true, false, false, true><<<384, 256, 0, stream>>>(
        h1, 96, bt_be2, bbe2, nullptr, 0, attn_in, 480, 320, nullptr, 0, 160, 96, 3);
    // attn_in -> a1 (relu), N=320, K=480
    gemm_k<false, true, false, false, false, true><<<640, 256, 0, stream>>>(
        attn_in, 480, bt_a1, ba1, nullptr, 0, a1b, 320, 0, nullptr, 0, 320, 480, 5);

    attn_fuse_kernel<<<64, 256, 0, stream>>>(a1b, Wa2, ba2, fpb, attn_out, fusedb);

    // fused -> h (relu), N=320, K=320
    gemm_k<false, true, false, false, false, true><<<640, 256, 0, stream>>>(
        fusedb, 320, bt_o1, bo1, nullptr, 0, hb, 320, 0, nullptr, 0, 320, 320, 5);
    // h -> out (+global residual), f32 to d_out
    gemm_k<false, false, false, true, true, false><<<640, 256, 0, stream>>>(
        hb, 320, bt_o2, bo2, outf, 320, nullptr, 0, 0, gf32, 320, 320, 320, 5);
}

// Round 4
// 177.926 us; speedup vs baseline: 3.4710x; 1.6869x over previous
//
#include <hip/hip_runtime.h>
#include <stdint.h>

typedef float fx4 __attribute__((ext_vector_type(4)));
typedef short s8 __attribute__((ext_vector_type(8)));
typedef short s4 __attribute__((ext_vector_type(4)));
typedef unsigned int u32;
typedef u32 ux4 __attribute__((ext_vector_type(4)));

#define MTOT 16384
#define NPTS 4096

__device__ __forceinline__ float b2f(short s) {
    return __uint_as_float(((unsigned)(unsigned short)s) << 16);
}
__device__ __forceinline__ short f2b(float f) {
    unsigned u = __float_as_uint(f);
    u += 0x7fffu + ((u >> 16) & 1u);
    return (short)(u >> 16);
}

// ---------------------------------------------------------------------------
// Fused weight transpose + bf16 convert for 9 weight matrices.
// W[K][N] f32 -> Bt[N][Kp] bf16 (zero pad K..Kp)
// ---------------------------------------------------------------------------
struct WTDesc {
    const float* W[9];
    short* Bt[9];
    int K[9];
    int N[9];
    int Kp[9];
    int base[10];
};

__global__ __launch_bounds__(256) void wtrans9_kernel(WTDesc d)
{
    int idx = blockIdx.x * 256 + threadIdx.x;
    if (idx >= d.base[9]) return;
    int s = 0;
#pragma unroll
    for (int t = 1; t < 9; ++t) if (idx >= d.base[t]) s = t;
    int local = idx - d.base[s];
    int Kp = d.Kp[s], K = d.K[s], N = d.N[s];
    int n = local / Kp, k = local - n * Kp;
    d.Bt[s][local] = (k < K) ? f2b(d.W[s][(size_t)k * N + n]) : (short)0;
}

// ---------------------------------------------------------------------------
// kNN part 1 (unchanged from R3)
// ---------------------------------------------------------------------------
#define SEGW 132

__global__ __launch_bounds__(512) void knn_part_kernel(
    const float* __restrict__ pos, u32* __restrict__ keys)
{
    __shared__ float xs[8 * SEGW], ys[8 * SEGW], zs[8 * SEGW];
    int bid = blockIdx.x;
    int b   = bid >> 8;
    int cc  = (bid >> 6) & 3;
    int pch = bid & 63;
    int tid = threadIdx.x;
    int jb  = cc << 10;

    for (int idx = tid; idx < 1024; idx += 512) {
        int seg = idx >> 7, o = idx & 127;
        const float* pp = pos + (size_t)(b * NPTS + jb + idx) * 3;
        xs[seg * SEGW + o] = pp[0];
        ys[seg * SEGW + o] = pp[1];
        zs[seg * SEGW + o] = pp[2];
    }
    __syncthreads();

    int lp = tid >> 3, q = tid & 7;
    int gi = pch * 64 + lp;
    const float* mp = pos + (size_t)(b * NPTS + gi) * 3;
    float mx = mp[0], my = mp[1], mz = mp[2];

    u32 hk[12];
#pragma unroll
    for (int k = 0; k < 12; ++k) hk[k] = 0xFFFFFFFFu;

    const float* xsq = xs + q * SEGW;
    const float* ysq = ys + q * SEGW;
    const float* zsq = zs + q * SEGW;
    int jg0 = jb + q * 128;

    for (int jj = 0; jj < 128; jj += 4) {
        fx4 xv = *reinterpret_cast<const fx4*>(xsq + jj);
        fx4 yv = *reinterpret_cast<const fx4*>(ysq + jj);
        fx4 zv = *reinterpret_cast<const fx4*>(zsq + jj);
#pragma unroll
        for (int u = 0; u < 4; ++u) {
            float dx = xv[u] - mx, dy = yv[u] - my, dz = zv[u] - mz;
            float d2 = fmaf(dx, dx, fmaf(dy, dy, dz * dz));
            int jg = jg0 + jj + u;
            u32 key = (__float_as_uint(d2) & 0xFFFFF000u) | (u32)jg;
            if (jg == gi) key = 0xFFFFFFFFu;
            if (key < hk[11]) {
                hk[11] = key;
#pragma unroll
                for (int k = 11; k >= 1; --k) {
                    u32 a = hk[k], bb = hk[k - 1];
                    u32 mn = (a < bb) ? a : bb;
                    u32 mxv = (a < bb) ? bb : a;
                    hk[k - 1] = mn; hk[k] = mxv;
                }
            }
        }
    }

    u32 out[12];
#pragma unroll
    for (int r = 0; r < 12; ++r) {
        u32 m = hk[0];
        u32 o1 = __shfl_xor(m, 4, 8); m = (o1 < m) ? o1 : m;
        u32 o2 = __shfl_xor(m, 2, 8); m = (o2 < m) ? o2 : m;
        u32 o3 = __shfl_xor(m, 1, 8); m = (o3 < m) ? o3 : m;
        if (m == hk[0]) {
#pragma unroll
            for (int k = 0; k < 11; ++k) hk[k] = hk[k + 1];
            hk[11] = 0xFFFFFFFFu;
        }
        out[r] = m;
    }

    size_t kb = ((size_t)(b * NPTS + gi) * 4 + cc) * 12;
    if (q == 0) *reinterpret_cast<ux4*>(&keys[kb])     = (ux4){out[0], out[1], out[2], out[3]};
    if (q == 1) *reinterpret_cast<ux4*>(&keys[kb + 4]) = (ux4){out[4], out[5], out[6], out[7]};
    if (q == 2) *reinterpret_cast<ux4*>(&keys[kb + 8]) = (ux4){out[8], out[9], out[10], out[11]};
}

// ---------------------------------------------------------------------------
// kNN part 2 (unchanged from R3)
// ---------------------------------------------------------------------------
__global__ __launch_bounds__(256) void knn_merge_kernel(
    const u32* __restrict__ keys, const int* __restrict__ labels,
    const float* __restrict__ logits, float* __restrict__ info32)
{
    __shared__ unsigned char labs[NPTS];
    int b  = blockIdx.x >> 6;
    int pc = blockIdx.x & 63;
    int tid = threadIdx.x;
    for (int idx = tid; idx < NPTS; idx += 256)
        labs[idx] = (unsigned char)labels[b * NPTS + idx];
    __syncthreads();

    int lp = tid >> 2, q = tid & 3;
    int gi = pc * 64 + lp;
    size_t kb = ((size_t)(b * NPTS + gi) * 4 + q) * 12;
    ux4 k0 = *reinterpret_cast<const ux4*>(&keys[kb]);
    ux4 k1 = *reinterpret_cast<const ux4*>(&keys[kb + 4]);
    ux4 k2 = *reinterpret_cast<const ux4*>(&keys[kb + 8]);
    u32 hk[12];
    hk[0] = k0[0]; hk[1] = k0[1]; hk[2] = k0[2]; hk[3] = k0[3];
    hk[4] = k1[0]; hk[5] = k1[1]; hk[6] = k1[2]; hk[7] = k1[3];
    hk[8] = k2[0]; hk[9] = k2[1]; hk[10] = k2[2]; hk[11] = k2[3];

    int mylab = (int)labs[gi];
    float sum_d = 0.f, sum_d2 = 0.f, sum_diff = 0.f, same_d = 0.f, bmin = 3.0e38f;
#pragma unroll
    for (int r = 0; r < 12; ++r) {
        u32 m = hk[0];
        u32 o1 = __shfl_xor(m, 2, 4); m = (o1 < m) ? o1 : m;
        u32 o2 = __shfl_xor(m, 1, 4); m = (o2 < m) ? o2 : m;
        if (m == hk[0]) {
#pragma unroll
            for (int k = 0; k < 11; ++k) hk[k] = hk[k + 1];
            hk[11] = 0xFFFFFFFFu;
        }
        float d = sqrtf(__uint_as_float(m & 0xFFFFF000u));
        int j = (int)(m & 0xFFFu);
        float isdiff = ((int)labs[j] != mylab) ? 1.0f : 0.0f;
        sum_d += d;
        sum_d2 = fmaf(d, d, sum_d2);
        sum_diff += isdiff;
        same_d = fmaf(d, 1.0f - isdiff, same_d);
        if (isdiff > 0.f) bmin = fminf(bmin, d);
    }

    if (q == 0) {
        float nsame = 12.0f - sum_diff;
        float mean_d = sum_d * (1.0f / 12.0f);
        float var = fmaxf(0.f, (sum_d2 - 12.0f * mean_d * mean_d) * (1.0f / 11.0f));
        float md_eps = mean_d + 1e-6f;
        float curvature = sqrtf(var) / md_eps;
        float density = 1.0f / md_eps;
        float same_dist = same_d / (nsame + 1e-6f);
        float bdist = (bmin < 2.9e38f) ? bmin : same_dist;
        float bscore = sum_diff * (1.0f / 12.0f);

        const float* lg = logits + (size_t)(b * NPTS + gi) * 17;
        float v[17];
        float vmax = -3.0e38f;
#pragma unroll
        for (int c = 0; c < 17; ++c) { v[c] = lg[c] * (1.0f / 0.75f); vmax = fmaxf(vmax, v[c]); }
        float ssum = 0.f;
#pragma unroll
        for (int c = 0; c < 17; ++c) { v[c] = expf(v[c] - vmax); ssum += v[c]; }
        float inv = 1.0f / ssum;
        float conf = 0.f, ent = 0.f;
#pragma unroll
        for (int c = 0; c < 17; ++c) {
            float pprob = v[c] * inv;
            conf = fmaxf(conf, pprob);
            ent += pprob * logf(pprob + 1e-8f);
        }
        ent = -ent * (1.0f / 2.8332133f);

        float* op = info32 + (size_t)(b * NPTS + gi) * 32;
        fx4 o0 = {bscore, conf, ent, density};
        fx4 o1v = {curvature, bdist, 0.f, 0.f};
        fx4 zz = {0.f, 0.f, 0.f, 0.f};
        *reinterpret_cast<fx4*>(op + 0)  = o0;
        *reinterpret_cast<fx4*>(op + 4)  = o1v;
        *reinterpret_cast<fx4*>(op + 8)  = zz;
        *reinterpret_cast<fx4*>(op + 12) = zz;
        *reinterpret_cast<fx4*>(op + 16) = zz;
        *reinterpret_cast<fx4*>(op + 20) = zz;
        *reinterpret_cast<fx4*>(op + 24) = zz;
        *reinterpret_cast<fx4*>(op + 28) = zz;
    }
}

// ---------------------------------------------------------------------------
// Generic bf16-MFMA GEMM (used for the small boundary-encoder MLP only).
// ---------------------------------------------------------------------------
template<bool AF32, bool RELU, bool NMASK, bool ADDF, bool OUTF, bool OUTB>
__global__ __launch_bounds__(256) void gemm_k(
    const void* __restrict__ Ap, int lda,
    const short* __restrict__ Bt,
    const float* __restrict__ bias,
    float* __restrict__ Cf, int ldcf,
    short* __restrict__ Cb, int ldcb, int cboff,
    const float* __restrict__ Af, int ldaf,
    int N, int K, int ntiles)
{
    __shared__ short As[128 * 40];
    __shared__ short Bs[64 * 40];
    int bid = blockIdx.x;
    int mt = bid / ntiles, nt = bid - mt * ntiles;
    int m0 = mt * 128, n0 = nt * 64;
    int tid = threadIdx.x, l = tid & 63, wid = tid >> 6;
    int wm = wid & 1, wn = wid >> 1, lr = l & 15, lh = l >> 4;
    fx4 acc[4][2] = {};

    int nsteps = K >> 5;
    for (int kt = 0; kt < nsteps; ++kt) {
        int k0 = kt << 5;
        if constexpr (AF32) {
            const float* A = (const float*)Ap;
#pragma unroll
            for (int it = 0; it < 4; ++it) {
                int tt = tid + it * 256;
                int row = tt >> 3, seg = tt & 7;
                fx4 vv = *reinterpret_cast<const fx4*>(A + (size_t)(m0 + row) * lda + k0 + seg * 4);
                s4 w; w[0] = f2b(vv[0]); w[1] = f2b(vv[1]); w[2] = f2b(vv[2]); w[3] = f2b(vv[3]);
                *reinterpret_cast<s4*>(&As[row * 40 + seg * 4]) = w;
            }
        } else {
            const short* A = (const short*)Ap;
#pragma unroll
            for (int it = 0; it < 2; ++it) {
                int tt = tid + it * 256;
                int row = tt >> 2, seg = tt & 3;
                s8 vv = *reinterpret_cast<const s8*>(A + (size_t)(m0 + row) * lda + k0 + seg * 8);
                *reinterpret_cast<s8*>(&As[row * 40 + seg * 8]) = vv;
            }
        }
        {
            int row = tid >> 2, seg = tid & 3;
            s8 vb = {0, 0, 0, 0, 0, 0, 0, 0};
            if (!NMASK || (n0 + row) < N)
                vb = *reinterpret_cast<const s8*>(Bt + (size_t)(n0 + row) * K + k0 + seg * 8);
            *reinterpret_cast<s8*>(&Bs[row * 40 + seg * 8]) = vb;
        }
        __syncthreads();
        s8 af[4], bfr[2];
#pragma unroll
        for (int mf = 0; mf < 4; ++mf)
            af[mf] = *reinterpret_cast<s8*>(&As[(wm * 64 + mf * 16 + lr) * 40 + lh * 8]);
#pragma unroll
        for (int nf = 0; nf < 2; ++nf)
            bfr[nf] = *reinterpret_cast<s8*>(&Bs[(wn * 32 + nf * 16 + lr) * 40 + lh * 8]);
#pragma unroll
        for (int mf = 0; mf < 4; ++mf)
#pragma unroll
            for (int nf = 0; nf < 2; ++nf)
                acc[mf][nf] = __builtin_amdgcn_mfma_f32_16x16x32_bf16(af[mf], bfr[nf], acc[mf][nf], 0, 0, 0);
        __syncthreads();
    }

#pragma unroll
    for (int nf = 0; nf < 2; ++nf) {
        int col = n0 + wn * 32 + nf * 16 + lr;
        if (NMASK && col >= N) continue;
        float bv = bias[col];
#pragma unroll
        for (int mf = 0; mf < 4; ++mf) {
            int r0 = m0 + wm * 64 + mf * 16 + lh * 4;
#pragma unroll
            for (int rg = 0; rg < 4; ++rg) {
                float c = acc[mf][nf][rg] + bv;
                if (RELU) c = fmaxf(c, 0.0f);
                int row = r0 + rg;
                if constexpr (ADDF) c += Af[(size_t)row * ldaf + col];
                if constexpr (OUTF) Cf[(size_t)row * ldcf + col] = c;
                if constexpr (OUTB) Cb[(size_t)row * ldcb + cboff + col] = f2b(c);
            }
        }
    }
}

// ---------------------------------------------------------------------------
// MEGA kernel: per block of 32 rows does the entire post-knn network.
// proj(3 scales, fp in regs) -> global -> a1 -> a2 -> softmax -> fused ->
// o1 -> o2 + residual. BN = 320 (full width), 4 waves x 80 cols.
// LDS: B-stage [320][40] @0, R2 31.2KB @12800 (attnA[32][488] then
// a1/fused/h [32][328]), Aproj [32][40] @28416, w [32][4] f32 @29696.
// ---------------------------------------------------------------------------
__global__ __launch_bounds__(256, 2) void mega_kernel(
    const float* __restrict__ f0, const float* __restrict__ f1, const float* __restrict__ f2,
    const short* __restrict__ btp0, const short* __restrict__ btp1, const short* __restrict__ btp2,
    const float* __restrict__ bp0, const float* __restrict__ bp1, const float* __restrict__ bp2,
    const short* __restrict__ bta1, const float* __restrict__ ba1,
    const short* __restrict__ bta2, const float* __restrict__ ba2,
    const short* __restrict__ bto1, const float* __restrict__ bo1,
    const short* __restrict__ bto2, const float* __restrict__ bo2,
    const short* __restrict__ encb, short* __restrict__ gbuf,
    float* __restrict__ outf, float* __restrict__ attn_out)
{
    __shared__ alignas(16) short smem[29952];
    constexpr int SB = 0, R2 = 12800, SAP = 28416, SW = 29696;
    float* smf = (float*)&smem[SW];

    int tid = threadIdx.x, l = tid & 63, wid = tid >> 6;
    int lr = l & 15, lh = l >> 4;
    int m0 = blockIdx.x * 32;

    auto loadB5 = [&](const short* src, int ldk, int k0, s8* d) {
#pragma unroll
        for (int r = 0; r < 5; ++r) {
            int idx = tid + r * 256;
            int row = idx >> 2, seg = idx & 3;
            d[r] = *reinterpret_cast<const s8*>(src + (size_t)row * ldk + k0 + seg * 8);
        }
    };
    auto storeB5 = [&](const s8* d) {
#pragma unroll
        for (int r = 0; r < 5; ++r) {
            int idx = tid + r * 256;
            int row = idx >> 2, seg = idx & 3;
            *reinterpret_cast<s8*>(&smem[SB + row * 40 + seg * 8]) = d[r];
        }
    };
    auto readBfrag = [&](s8* bf) {
#pragma unroll
        for (int nf = 0; nf < 5; ++nf)
            bf[nf] = *reinterpret_cast<s8*>(&smem[SB + (wid * 80 + nf * 16 + lr) * 40 + lh * 8]);
    };

    fx4 gacc[2][5] = {};
    s4 fpk[3][2][5];

    auto do_proj = [&](const float* A, int K, const short* bt, const float* bias, int s) {
        fx4 acc[2][5] = {};
        int ns = K >> 5;
        s8 bP[5]; fx4 aP;
        loadB5(bt, K, 0, bP);
        {
            int row = tid >> 3, seg = tid & 7;
            aP = *reinterpret_cast<const fx4*>(A + (size_t)(m0 + row) * K + seg * 4);
        }
#pragma unroll 1
        for (int kt = 0; kt < ns; ++kt) {
            s8 bC[5]; fx4 aC = aP;
#pragma unroll
            for (int r = 0; r < 5; ++r) bC[r] = bP[r];
            if (kt + 1 < ns) {
                loadB5(bt, K, (kt + 1) * 32, bP);
                int row = tid >> 3, seg = tid & 7;
                aP = *reinterpret_cast<const fx4*>(A + (size_t)(m0 + row) * K + (kt + 1) * 32 + seg * 4);
            }
            __syncthreads();
            storeB5(bC);
            {
                int row = tid >> 3, seg = tid & 7;
                s4 w; w[0] = f2b(aC[0]); w[1] = f2b(aC[1]); w[2] = f2b(aC[2]); w[3] = f2b(aC[3]);
                *reinterpret_cast<s4*>(&smem[SAP + row * 40 + seg * 4]) = w;
            }
            __syncthreads();
            s8 af[2], bf[5];
#pragma unroll
            for (int mf = 0; mf < 2; ++mf)
                af[mf] = *reinterpret_cast<s8*>(&smem[SAP + (mf * 16 + lr) * 40 + lh * 8]);
            readBfrag(bf);
#pragma unroll
            for (int mf = 0; mf < 2; ++mf)
#pragma unroll
                for (int nf = 0; nf < 5; ++nf)
                    acc[mf][nf] = __builtin_amdgcn_mfma_f32_16x16x32_bf16(af[mf], bf[nf], acc[mf][nf], 0, 0, 0);
        }
#pragma unroll
        for (int nf = 0; nf < 5; ++nf) {
            float bv = bias[wid * 80 + nf * 16 + lr];
#pragma unroll
            for (int mf = 0; mf < 2; ++mf) {
                s4 pk;
#pragma unroll
                for (int rg = 0; rg < 4; ++rg) {
                    float c = acc[mf][nf][rg] + bv;
                    gacc[mf][nf][rg] += c;
                    pk[rg] = f2b(c);
                }
                fpk[s][mf][nf] = pk;
            }
        }
    };

    // heaviest K first: fpk mostly empty during the long loop (reg pressure)
    do_proj(f2, 768, btp2, bp2, 2);
    do_proj(f1, 512, btp1, bp1, 1);
    do_proj(f0, 256, btp0, bp0, 0);

    // global = mean -> attnA LDS (bf16) + gbuf HBM (bf16, for o2 residual)
#pragma unroll
    for (int nf = 0; nf < 5; ++nf) {
        int col = wid * 80 + nf * 16 + lr;
#pragma unroll
        for (int mf = 0; mf < 2; ++mf)
#pragma unroll
            for (int rg = 0; rg < 4; ++rg) {
                int row = mf * 16 + lh * 4 + rg;
                float g = gacc[mf][nf][rg] * (1.0f / 3.0f);
                short gs = f2b(g);
                smem[R2 + row * 488 + col] = gs;
                gbuf[(size_t)(m0 + row) * 320 + col] = gs;
            }
    }
    // stage enc (cols 320..479 of attnA)
#pragma unroll
    for (int r = 0; r < 3; ++r) {
        int idx = tid + r * 256;
        if (idx < 640) {
            int row = idx / 20, sg = idx - row * 20;
            s8 v = *reinterpret_cast<const s8*>(encb + (size_t)(m0 + row) * 160 + sg * 8);
            *reinterpret_cast<s8*>(&smem[R2 + row * 488 + 320 + sg * 8]) = v;
        }
    }

    // generic GEMM with A resident in LDS, B prefetch-staged per K-step
    auto do_gemm = [&](int abase, int astr, const short* bt, int ldk, fx4 acc[2][5]) {
        int ns = ldk >> 5;
        s8 bP[5];
        loadB5(bt, ldk, 0, bP);
#pragma unroll 1
        for (int kt = 0; kt < ns; ++kt) {
            s8 bC[5];
#pragma unroll
            for (int r = 0; r < 5; ++r) bC[r] = bP[r];
            if (kt + 1 < ns) loadB5(bt, ldk, (kt + 1) * 32, bP);
            __syncthreads();
            storeB5(bC);
            __syncthreads();
            s8 af[2], bf[5];
#pragma unroll
            for (int mf = 0; mf < 2; ++mf)
                af[mf] = *reinterpret_cast<s8*>(&smem[abase + (mf * 16 + lr) * astr + kt * 32 + lh * 8]);
            readBfrag(bf);
#pragma unroll
            for (int mf = 0; mf < 2; ++mf)
#pragma unroll
                for (int nf = 0; nf < 5; ++nf)
                    acc[mf][nf] = __builtin_amdgcn_mfma_f32_16x16x32_bf16(af[mf], bf[nf], acc[mf][nf], 0, 0, 0);
        }
        __syncthreads();
    };

    // ---- a1 = relu([global|enc] @ Wa1 + ba1), K=480
    {
        fx4 acc1[2][5] = {};
        do_gemm(R2, 488, bta1, 480, acc1);
        // write a1 (bf16) over R2 with stride 328 (attnA dead now)
#pragma unroll
        for (int nf = 0; nf < 5; ++nf) {
            int col = wid * 80 + nf * 16 + lr;
            float bv = ba1[col];
#pragma unroll
            for (int mf = 0; mf < 2; ++mf)
#pragma unroll
                for (int rg = 0; rg < 4; ++rg) {
                    int row = mf * 16 + lh * 4 + rg;
                    float c = fmaxf(acc1[mf][nf][rg] + bv, 0.0f);
                    smem[R2 + row * 328 + col] = f2b(c);
                }
        }
        __syncthreads();
    }

    // ---- a2 = a1 @ Wa2 + ba2 (N=3, padded to 16; all waves redundant)
    {
        fx4 acc2[2] = {};
#pragma unroll 1
        for (int kt = 0; kt < 10; ++kt) {
            __syncthreads();
            if (tid < 64) {
                int row = tid >> 2, seg = tid & 3;
                s8 v = {0, 0, 0, 0, 0, 0, 0, 0};
                if (row < 3) v = *reinterpret_cast<const s8*>(bta2 + row * 320 + kt * 32 + seg * 8);
                *reinterpret_cast<s8*>(&smem[SAP + row * 40 + seg * 8]) = v;
            }
            __syncthreads();
            s8 af[2];
#pragma unroll
            for (int mf = 0; mf < 2; ++mf)
                af[mf] = *reinterpret_cast<s8*>(&smem[R2 + (mf * 16 + lr) * 328 + kt * 32 + lh * 8]);
            s8 b2v = *reinterpret_cast<s8*>(&smem[SAP + lr * 40 + lh * 8]);
#pragma unroll
            for (int mf = 0; mf < 2; ++mf)
                acc2[mf] = __builtin_amdgcn_mfma_f32_16x16x32_bf16(af[mf], b2v, acc2[mf], 0, 0, 0);
        }
        __syncthreads();
        if (wid == 0 && lr < 3) {
#pragma unroll
            for (int mf = 0; mf < 2; ++mf)
#pragma unroll
                for (int rg = 0; rg < 4; ++rg) {
                    int row = mf * 16 + lh * 4 + rg;
                    smf[row * 4 + lr] = acc2[mf][rg] + ba2[lr];
                }
        }
        __syncthreads();
        if (tid < 32) {
            float l0 = smf[tid * 4 + 0], l1 = smf[tid * 4 + 1], l2 = smf[tid * 4 + 2];
            float mx = fmaxf(l0, fmaxf(l1, l2));
            float e0 = expf(l0 - mx), e1 = expf(l1 - mx), e2 = expf(l2 - mx);
            float inv = 1.0f / (e0 + e1 + e2);
            float w0 = e0 * inv, w1 = e1 * inv, w2 = e2 * inv;
            attn_out[(size_t)(m0 + tid) * 3 + 0] = w0;
            attn_out[(size_t)(m0 + tid) * 3 + 1] = w1;
            attn_out[(size_t)(m0 + tid) * 3 + 2] = w2;
            smf[tid * 4 + 0] = w0; smf[tid * 4 + 1] = w1; smf[tid * 4 + 2] = w2;
        }
        __syncthreads();
    }

    // ---- fused = sum_s w_s * fp_s -> bf16 into R2 (overwrites a1)
#pragma unroll
    for (int mf = 0; mf < 2; ++mf)
#pragma unroll
        for (int rg = 0; rg < 4; ++rg) {
            int row = mf * 16 + lh * 4 + rg;
            fx4 wv = *reinterpret_cast<fx4*>(&smf[row * 4]);
#pragma unroll
            for (int nf = 0; nf < 5; ++nf) {
                float fv = wv[0] * b2f(fpk[0][mf][nf][rg])
                         + wv[1] * b2f(fpk[1][mf][nf][rg])
                         + wv[2] * b2f(fpk[2][mf][nf][rg]);
                smem[R2 + row * 328 + wid * 80 + nf * 16 + lr] = f2b(fv);
            }
        }
    __syncthreads();

    // ---- h = relu(fused @ Wo1 + bo1)
    {
        fx4 acch[2][5] = {};
        do_gemm(R2, 328, bto1, 320, acch);
#pragma unroll
        for (int nf = 0; nf < 5; ++nf) {
            int col = wid * 80 + nf * 16 + lr;
            float bv = bo1[col];
#pragma unroll
            for (int mf = 0; mf < 2; ++mf)
#pragma unroll
                for (int rg = 0; rg < 4; ++rg) {
                    int row = mf * 16 + lh * 4 + rg;
                    float c = fmaxf(acch[mf][nf][rg] + bv, 0.0f);
                    smem[R2 + row * 328 + col] = f2b(c);
                }
        }
        __syncthreads();
    }

    // ---- out = h @ Wo2 + bo2 + global (residual from gbuf)
    {
        fx4 acco[2][5] = {};
        do_gemm(R2, 328, bto2, 320, acco);
#pragma unroll
        for (int nf = 0; nf < 5; ++nf) {
            int col = wid * 80 + nf * 16 + lr;
            float bv = bo2[col];
#pragma unroll
            for (int mf = 0; mf < 2; ++mf)
#pragma unroll
                for (int rg = 0; rg < 4; ++rg) {
                    int row = m0 + mf * 16 + lh * 4 + rg;
                    float c = acco[mf][nf][rg] + bv + b2f(gbuf[(size_t)row * 320 + col]);
                    outf[(size_t)row * 320 + col] = c;
                }
        }
    }
}

// ---------------------------------------------------------------------------
extern "C" void kernel_launch(void* const* d_in, const int* in_sizes, int n_in,
                              void* d_out, int out_size, void* d_ws, size_t ws_size,
                              hipStream_t stream)
{
    const float* feat0  = (const float*)d_in[0];
    const float* feat1  = (const float*)d_in[1];
    const float* feat2  = (const float*)d_in[2];
    const float* logits = (const float*)d_in[3];
    const int*   labels = (const int*)d_in[4];
    const float* pos    = (const float*)d_in[5];
    const float* Wp0 = (const float*)d_in[6];   const float* bp0 = (const float*)d_in[7];
    const float* Wp1 = (const float*)d_in[8];   const float* bp1 = (const float*)d_in[9];
    const float* Wp2 = (const float*)d_in[10];  const float* bp2 = (const float*)d_in[11];
    const float* Wbe1 = (const float*)d_in[12]; const float* bbe1 = (const float*)d_in[13];
    const float* Wbe2 = (const float*)d_in[14]; const float* bbe2 = (const float*)d_in[15];
    const float* Wa1 = (const float*)d_in[16];  const float* ba1 = (const float*)d_in[17];
    const float* Wa2 = (const float*)d_in[18];  const float* ba2 = (const float*)d_in[19];
    const float* Wo1 = (const float*)d_in[20];  const float* bo1 = (const float*)d_in[21];
    const float* Wo2 = (const float*)d_in[22];  const float* bo2 = (const float*)d_in[23];

    char* p = (char*)d_ws;
    auto alloc = [&](size_t bytes) { char* r = p; p += (bytes + 255) & ~(size_t)255; return r; };
    short* bt_p0  = (short*)alloc((size_t)320 * 256 * 2);
    short* bt_p1  = (short*)alloc((size_t)320 * 512 * 2);
    short* bt_p2  = (short*)alloc((size_t)320 * 768 * 2);
    short* bt_be1 = (short*)alloc((size_t)96 * 32 * 2);
    short* bt_be2 = (short*)alloc((size_t)160 * 96 * 2);
    short* bt_a1  = (short*)alloc((size_t)320 * 480 * 2);
    short* bt_a2  = (short*)alloc((size_t)3 * 320 * 2);
    short* bt_o1  = (short*)alloc((size_t)320 * 320 * 2);
    short* bt_o2  = (short*)alloc((size_t)320 * 320 * 2);
    float* info32 = (float*)alloc((size_t)MTOT * 32 * 4);
    short* h1     = (short*)alloc((size_t)MTOT * 96 * 2);
    short* encb   = (short*)alloc((size_t)MTOT * 160 * 2);
    short* gbuf   = (short*)alloc((size_t)MTOT * 320 * 2);
    u32*   knnkeys= (u32*)alloc((size_t)MTOT * 4 * 12 * 4);

    float* outf = (float*)d_out;
    float* attn_out = outf + (size_t)MTOT * 320;

    WTDesc wd;
    const float* Ws[9] = {Wp0, Wp1, Wp2, Wbe1, Wbe2, Wa1, Wa2, Wo1, Wo2};
    short* Bts[9] = {bt_p0, bt_p1, bt_p2, bt_be1, bt_be2, bt_a1, bt_a2, bt_o1, bt_o2};
    int Ks[9]  = {256, 512, 768, 6, 96, 480, 320, 320, 320};
    int Ns[9]  = {320, 320, 320, 96, 160, 320, 3, 320, 320};
    int Kps[9] = {256, 512, 768, 32, 96, 480, 320, 320, 320};
    int acc = 0;
    for (int s = 0; s < 9; ++s) {
        wd.W[s] = Ws[s]; wd.Bt[s] = Bts[s];
        wd.K[s] = Ks[s]; wd.N[s] = Ns[s]; wd.Kp[s] = Kps[s];
        wd.base[s] = acc;
        acc += Ns[s] * Kps[s];
    }
    wd.base[9] = acc;
    wtrans9_kernel<<<(acc + 255) / 256, 256, 0, stream>>>(wd);

    knn_part_kernel<<<1024, 512, 0, stream>>>(pos, knnkeys);
    knn_merge_kernel<<<256, 256, 0, stream>>>(knnkeys, labels, logits, info32);

    // info -> h1 (relu), N=96, K=32
    gemm_k<true, true, true, false, false, true><<<256, 256, 0, stream>>>(
        info32, 32, bt_be1, bbe1, nullptr, 0, h1, 96, 0, nullptr, 0, 96, 32, 2);
    // h1 -> enc (relu), N=160, K=96
    gemm_k<false, true, true, false, false, true><<<384, 256, 0, stream>>>(
        h1, 96, bt_be2, bbe2, nullptr, 0, encb, 160, 0, nullptr, 0, 160, 96, 3);

    mega_kernel<<<512, 256, 0, stream>>>(
        feat0, feat1, feat2,
        bt_p0, bt_p1, bt_p2,
        bp0, bp1, bp2,
        bt_a1, ba1, bt_a2, ba2,
        bt_o1, bo1, bt_o2, bo2,
        encb, gbuf, outf, attn_out);
}